// Round 10
// baseline (327.637 us; speedup 1.0000x reference)
//
#include <hip/hip_runtime.h>

// ---------------------------------------------------------------------------
// MaximumMeanDiscrepancy: BATCH=160, INSTANCES=4, FEAT=1024, P=40
// out[0] = mmd(wcs, wct), out[1] = mmd(bcs, bct)
// ---------------------------------------------------------------------------

#define FEAT   1024
#define NROW   160     // BATCH
#define NBC    6088    // (1 + 39*39) * 4
#define NWC    160

// workspace layout (float offsets). bci/wci INTERLEAVED: row i = {src f4, tgt f4}.
// 256 pad rows of 1e19f follow each array (pad d -> clamps to zeroed top table
// cell -> contributes exactly 0, never hot). The global PL table (SoA:
// base[2048] then slope[2048]) lives in the dead E_t region (E dead after
// scatter; build_tab runs after scatter).
#define WS_ES   0          // E_s [160*160]
#define WS_ET   25600      // E_t [160*160]  (later: PL table, 4096 floats)
#define WS_TAB  25600
#define WS_BCI  51200      // bci [(6088+256)*8]
#define WS_WCI  101952     // wci [(160+256)*8]
#define WS_ACC_BYTES 421120  // 6*64 doubles
#define WS_CTR_BYTES 424192  // int work counter
#define NSLOT  64

// PL table: sum of sigma in {20,25,30,35,100,1e3,1e4,1e5,1e6} over d in
// [2048, 2^25), 128 cells/octave, bits-indexed by (float_bits>>16)-17664.
// Cells >= 1792 (d >= 2^25, where the sum < 7e-8 and P(d)~e^-1000) are exact 0
// so the top-clamp (incl. 1e19 padding) contributes nothing.
// hot (queue) threshold: cell t < 67  <=>  d < 3120.0f (sigma<=15 tier).
#define TAB_N    2048
#define TAB_LIVE 1792
#define TAB_BASE 17664     // bits(2048.f) >> 16
#define HOT_CELL 67

// persistent-block work items, pulled via atomic counter:
//   [0, 24352)       bc pair-eighths: p = g>>3 rows {p,6087-p}, trip stride 8
//   [24352, 24432)   wc pairs {i, 159-i}
//   [24432, 24457)   st-diag strips (24 bc + 1 wc)
#define IT_BC_END 24352
#define IT_WC_END 24432
#define NITEMS    24457
#define GK_GRID   1792     // 7 blocks/CU x 256 CUs, all co-resident

struct Coef { float c[19]; };  // c[k] = -log2(e)/(2*sigma_k)  (exp2 form)

#if defined(__has_builtin)
#if __has_builtin(__builtin_amdgcn_exp2f)
#define EXP2(x) __builtin_amdgcn_exp2f(x)
#else
#define EXP2(x) exp2f(x)
#endif
#else
#define EXP2(x) exp2f(x)
#endif

// --- kernel 1: E[a,b] = ||f_a - f_b||^2 for both sides, 16x16 tiles ---------
__global__ __launch_bounds__(256) void compute_E(const float* __restrict__ Fs,
                                                 const float* __restrict__ Ft,
                                                 float* __restrict__ ws) {
    int side = blockIdx.x / 100;          // 0 = source, 1 = target
    int tile = blockIdx.x % 100;
    int trow = tile / 10, tcol = tile % 10;
    const float* F = side ? Ft : Fs;
    float* E = ws + (side ? WS_ET : WS_ES);

    __shared__ float As[16][132];
    __shared__ float Bs[16][132];
    int tid = threadIdx.x;
    int ti = tid >> 4, tj = tid & 15;
    int lr = tid >> 5;        // 0..7
    int lc4 = tid & 31;       // float4 column (0..31) of 128-dim chunk

    float acc = 0.f;
    for (int ch = 0; ch < 8; ++ch) {
        for (int rr = lr; rr < 16; rr += 8) {
            float4 a = *(const float4*)(F + (trow*16+rr)*FEAT + ch*128 + lc4*4);
            *(float4*)(&As[rr][lc4*4]) = a;
            float4 b = *(const float4*)(F + (tcol*16+rr)*FEAT + ch*128 + lc4*4);
            *(float4*)(&Bs[rr][lc4*4]) = b;
        }
        __syncthreads();
        #pragma unroll
        for (int c = 0; c < 128; c += 4) {
            float4 a = *(const float4*)(&As[ti][c]);
            float4 b = *(const float4*)(&Bs[tj][c]);
            float d0 = a.x - b.x, d1 = a.y - b.y, d2 = a.z - b.z, d3 = a.w - b.w;
            acc = fmaf(d0, d0, acc);
            acc = fmaf(d1, d1, acc);
            acc = fmaf(d2, d2, acc);
            acc = fmaf(d3, d3, acc);
        }
        __syncthreads();
    }
    E[(trow*16+ti)*NROW + tcol*16 + tj] = acc;
}

// --- kernel 2: gather interleaved bci/wci rows; pad; zero accs + counter ----
__global__ __launch_bounds__(256) void scatter(float* __restrict__ ws) {
    int idx = blockIdx.x * blockDim.x + threadIdx.x;
    const float* E_s = ws + WS_ES;
    const float* E_t = ws + WS_ET;
    float4* bci = (float4*)(ws + WS_BCI);
    float4* wci = (float4*)(ws + WS_WCI);
    double* accs = (double*)((char*)ws + WS_ACC_BYTES);

    if (idx < 6 * NSLOT) accs[idx] = 0.0;
    if (idx == 6 * NSLOT) *(int*)((char*)ws + WS_CTR_BYTES) = 0;

    if (idx < NBC) {
        int t = idx >> 2, ii = idx & 3;
        int pi, pj;
        if (t == 0) { pi = 0; pj = 1; }
        else {
            int tt = t - 1;
            pi = 1 + tt / 39;
            int jj = tt % 39;
            pj = (jj < pi) ? jj : jj + 1;
        }
        bci[2*idx]   = *(const float4*)(E_s + (4*pi + ii)*NROW + 4*pj);
        bci[2*idx+1] = *(const float4*)(E_t + (4*pi + ii)*NROW + 4*pj);
    } else if (idx < NBC + NWC) {
        int r = idx - NBC;
        int p = r >> 2;
        wci[2*r]   = *(const float4*)(E_s + r*NROW + 4*p);
        wci[2*r+1] = *(const float4*)(E_t + r*NROW + 4*p);
    } else if (idx < NBC + NWC + 256) {
        int p = NBC + (idx - (NBC + NWC));
        float4 pad = make_float4(1e19f, 1e19f, 1e19f, 1e19f);
        bci[2*p] = pad;
        bci[2*p+1] = pad;
    } else if (idx < NBC + NWC + 512) {
        int p = NWC + (idx - (NBC + NWC + 256));
        float4 pad = make_float4(1e19f, 1e19f, 1e19f, 1e19f);
        wci[2*p] = pad;
        wci[2*p+1] = pad;
    }
}

// --- exact term helpers ------------------------------------------------------
// Tier-skip is exact: exp2(d*c) == 0.0f once d*c <= -150:
// sigma<=35 -> d>=7279; sigma<=15 -> d>=3120; sigma<=1 -> 208.
__device__ __forceinline__ float tail_sum(float d, const Coef& co) {
    float s = EXP2(d * co.c[10]) + EXP2(d * co.c[11])
            + EXP2(d * co.c[12]) + EXP2(d * co.c[13]);   // 20,25,30,35
    if (d < 3120.0f)
        s += EXP2(d * co.c[7]) + EXP2(d * co.c[8]) + EXP2(d * co.c[9]); // 5,10,15
    if (d < 208.0f)
        s += EXP2(d * co.c[0]) + EXP2(d * co.c[1]) + EXP2(d * co.c[2])
           + EXP2(d * co.c[3]) + EXP2(d * co.c[4]) + EXP2(d * co.c[5])
           + EXP2(d * co.c[6]);                           // sigma <= 1
    return s;
}
// big-5: sigma = 100, 1e3, 1e4, 1e5, 1e6 (exact)
__device__ __forceinline__ float big5(float d, const Coef& co) {
    return EXP2(d * co.c[14]) + EXP2(d * co.c[15]) + EXP2(d * co.c[16])
         + EXP2(d * co.c[17]) + EXP2(d * co.c[18]);
}
// big-9 (table contents): sigma = 20..35, 100, 1e3..1e6
__device__ __forceinline__ float big9(float d, const Coef& co) {
    float s = 0.f;
    #pragma unroll
    for (int k = 10; k < 19; ++k) s += EXP2(d * co.c[k]);
    return s;
}

__device__ __forceinline__ float sqd(float4 a, float4 b) {
    float d0 = a.x - b.x, d1 = a.y - b.y, d2 = a.z - b.z, d3 = a.w - b.w;
    float d = d0 * d0;
    d = fmaf(d1, d1, d);
    d = fmaf(d2, d2, d);
    return fmaf(d3, d3, d);
}

// --- kernel 2b: build the global PL table, SoA (dead E_t region) ------------
// midpoint-corrected chord per cell; cells never cross an exponent boundary.
__global__ __launch_bounds__(256) void build_tab(float* __restrict__ ws, Coef co) {
    int k = blockIdx.x * 256 + threadIdx.x;
    if (k >= TAB_N) return;
    float base = 0.f, slope = 0.f;
    if (k < TAB_LIVE) {
        unsigned u_lo = (unsigned)(TAB_BASE + k) << 16;
        float d_lo = __uint_as_float(u_lo);
        float d_mi = __uint_as_float(u_lo + 0x8000u);
        float d_hi = __uint_as_float(u_lo + 0x10000u);
        float f_lo = big9(d_lo, co), f_mi = big9(d_mi, co), f_hi = big9(d_hi, co);
        base  = f_lo + 0.5f * (f_mi - 0.5f * (f_lo + f_hi));
        slope = (f_hi - f_lo) * (1.0f / 65536.0f);
    }
    ws[WS_TAB + k] = base;
    ws[WS_TAB + TAB_N + k] = slope;
}

// --- kernel 3: persistent-block fused sweep with atomic work stealing -------
// 1792 co-resident blocks pull items off a global counter. Per trip: 2 f4
// loads, 4 sqd, 4 SoA table lookups (b32 gathers over 32 banks), zero inline
// exps. Hot pairs (cell<67, ~0.43%/eval) -> 3 per-wave LDS queues guarded by
// one __any per trip; drain adds big5+tail-tab(d) so the inline lookup
// cancels exactly. Queues hold one job class; flushed at the bc->wc boundary.
__global__ __launch_bounds__(256, 7) void gk_persist(float* __restrict__ ws, Coef co) {
    const float4* bci = (const float4*)(ws + WS_BCI);
    const float4* wci = (const float4*)(ws + WS_WCI);
    double* accs = (double*)((char*)ws + WS_ACC_BYTES);
    int* ctr = (int*)((char*)ws + WS_CTR_BYTES);

    __shared__ float tab[2 * TAB_N];      // [0:2048) base, [2048:4096) slope
    __shared__ float qb[4][3][128];
    __shared__ double wsum[4][6];
    __shared__ int s_item;

    int tid = threadIdx.x;
    int lane = tid & 63, w = tid >> 6;

    {   // copy PL table global -> LDS (4 x float4 per thread)
        const float4* tg = (const float4*)(ws + WS_TAB);
        float4* td = (float4*)tab;
        for (int k = tid; k < TAB_N / 2; k += 256) td[k] = tg[k];
    }
    const float* tb  = tab;
    const float* tsl = tab + TAB_N;

    auto tab_get = [&](float d) -> float {
        unsigned u = __float_as_uint(d);
        int t = (int)(u >> 16) - TAB_BASE;
        t = min(max(t, 0), TAB_N - 1);
        return fmaf((float)(u & 0xFFFFu), tsl[t], tb[t]);
    };
    auto drain_term = [&](float d) -> float {
        return big5(d, co) + tail_sum(d, co) - tab_get(d);
    };

    int qn0 = 0, qn1 = 0, qn2 = 0;
    double a0 = 0.0, a1 = 0.0, a2 = 0.0, a3 = 0.0, a4 = 0.0, a5 = 0.0;

#define MBCNT(m) __builtin_amdgcn_mbcnt_hi((unsigned)((m) >> 32), \
                  __builtin_amdgcn_mbcnt_lo((unsigned)(m), 0u))
#define PUSHQ(Q, QN, dv, h) { unsigned long long m_ = __ballot(h); \
        if (h) qb[w][Q][(QN) + MBCNT(m_)] = (dv); \
        (QN) += (int)__popcll(m_); }

    auto flush3 = [&](double& A0, double& A1, double& A2) {
        if (lane < qn0) A0 += (double)drain_term(qb[w][0][lane]);
        if (lane < qn1) A1 += (double)drain_term(qb[w][1][lane]);
        if (lane < qn2) A2 += (double)drain_term(qb[w][2][lane]);
        qn0 = qn1 = qn2 = 0;
    };

    auto process = [&](const float4* __restrict__ Yv, int N, int i,
                       int par, int S, double& A0, double& A1, double& A2) {
        int T = (N - i - 1 + 255) >> 8;
        int trips = (T - par + S - 1) / S;
        if (trips <= 0) return;
        float4 xs = Yv[2*i], xt = Yv[2*i+1];
        const float4* Yp = Yv + 2*((i + 1) + par*256 + tid);
        int stride = 512 * S;
        float m0 = 0.f, m1 = 0.f, m2 = 0.f;
        for (int t = 0; t < trips; ++t) {
            float4 ys = Yp[0], yt = Yp[1];
            Yp += stride;
            float dss = sqd(xs, ys), dtt = sqd(xt, yt);
            float dst = sqd(xs, yt), dts = sqd(xt, ys);
            unsigned u0 = __float_as_uint(dss), u1 = __float_as_uint(dtt);
            unsigned u2 = __float_as_uint(dst), u3 = __float_as_uint(dts);
            int t0 = (int)(u0 >> 16) - TAB_BASE, t1 = (int)(u1 >> 16) - TAB_BASE;
            int t2 = (int)(u2 >> 16) - TAB_BASE, t3 = (int)(u3 >> 16) - TAB_BASE;
            bool h0 = t0 < HOT_CELL, h1 = t1 < HOT_CELL;
            bool h2 = t2 < HOT_CELL, h3 = t3 < HOT_CELL;
            t0 = min(max(t0, 0), TAB_N - 1);
            t1 = min(max(t1, 0), TAB_N - 1);
            t2 = min(max(t2, 0), TAB_N - 1);
            t3 = min(max(t3, 0), TAB_N - 1);
            m0 += fmaf((float)(u0 & 0xFFFFu), tsl[t0], tb[t0]);
            m1 += fmaf((float)(u1 & 0xFFFFu), tsl[t1], tb[t1]);
            m2 += fmaf((float)(u2 & 0xFFFFu), tsl[t2], tb[t2])
                + fmaf((float)(u3 & 0xFFFFu), tsl[t3], tb[t3]);
            if (__any(h0 | h1 | h2 | h3)) {
                PUSHQ(0, qn0, dss, h0);
                if (qn0 >= 64) { qn0 -= 64; m0 += drain_term(qb[w][0][qn0 + lane]); }
                PUSHQ(1, qn1, dtt, h1);
                if (qn1 >= 64) { qn1 -= 64; m1 += drain_term(qb[w][1][qn1 + lane]); }
                PUSHQ(2, qn2, dst, h2);
                if (qn2 >= 64) { qn2 -= 64; m2 += drain_term(qb[w][2][qn2 + lane]); }
                PUSHQ(2, qn2, dts, h3);
                if (qn2 >= 64) { qn2 -= 64; m2 += drain_term(qb[w][2][qn2 + lane]); }
            }
        }
        A0 += (double)m0; A1 += (double)m1; A2 += (double)m2;
    };

    int curbc = 1;   // queues currently hold bc-class entries
    for (;;) {
        __syncthreads();                       // all waves done with prev item/copy
        if (tid == 0) s_item = atomicAdd(ctr, 1);
        __syncthreads();
        int g = s_item;
        if (g >= IT_BC_END && curbc) { flush3(a3, a4, a5); curbc = 0; }
        if (g >= NITEMS) break;
        if (g < IT_BC_END) {                   // bc pair-eighth
            int p = g >> 3, oc = g & 7;
            process(bci, NBC, p,        oc, 8, a3, a4, a5);
            process(bci, NBC, 6087 - p, oc, 8, a3, a4, a5);
        } else if (g < IT_WC_END) {            // wc pair
            int i = g - IT_BC_END;
            process(wci, NWC, i,       0, 1, a0, a1, a2);
            process(wci, NWC, 159 - i, 0, 1, a0, a1, a2);
        } else {                               // st-diag strips (exact path)
            int s = g - IT_WC_END;
            if (s < 24) {
                int i0 = s * 256 + tid;
                if (i0 < NBC) {
                    float d = sqd(bci[2*i0], bci[2*i0+1]);
                    float sv = big5(d, co);
                    if (d < 7280.0f) sv += tail_sum(d, co);
                    a5 += (double)sv;
                }
            } else {
                if (tid < NWC) {
                    float d = sqd(wci[2*tid], wci[2*tid+1]);
                    float sv = big5(d, co);
                    if (d < 7280.0f) sv += tail_sum(d, co);
                    a2 += (double)sv;
                }
            }
        }
    }
    flush3(a0, a1, a2);                        // wc leftovers (curbc==0 at exit)

    // wave reduce, then block reduce 4 waves, 6 jobs
    #pragma unroll
    for (int off = 32; off; off >>= 1) {
        a0 += __shfl_down(a0, off, 64);
        a1 += __shfl_down(a1, off, 64);
        a2 += __shfl_down(a2, off, 64);
        a3 += __shfl_down(a3, off, 64);
        a4 += __shfl_down(a4, off, 64);
        a5 += __shfl_down(a5, off, 64);
    }
    if (lane == 0) {
        wsum[w][0] = a0; wsum[w][1] = a1; wsum[w][2] = a2;
        wsum[w][3] = a3; wsum[w][4] = a4; wsum[w][5] = a5;
    }
    __syncthreads();
    if (tid < 6) {
        double tot = wsum[0][tid] + wsum[1][tid] + wsum[2][tid] + wsum[3][tid];
        atomicAdd(&accs[tid * NSLOT + (blockIdx.x & (NSLOT - 1))], tot);
    }
#undef PUSHQ
#undef MBCNT
}

// --- kernel 4: combine into the two output scalars --------------------------
__global__ void finalize(const float* __restrict__ ws, float* __restrict__ out) {
    const double* accs = (const double*)((const char*)ws + WS_ACC_BYTES);
    int lane = threadIdx.x;  // blockDim = 64
    double p[6];
    #pragma unroll
    for (int q = 0; q < 6; ++q) {
        p[q] = accs[q * NSLOT + lane];
        #pragma unroll
        for (int off = 32; off; off >>= 1) p[q] += __shfl_down(p[q], off, 64);
    }
    if (lane == 0) {
        double t0 = 2.0 * p[0] + 19.0 * NWC;   // self: 2*triangle + diag
        double t1 = 2.0 * p[1] + 19.0 * NWC;
        double t3 = 2.0 * p[3] + 19.0 * NBC;
        double t4 = 2.0 * p[4] + 19.0 * NBC;
        double nw = (double)NWC * (double)NWC;
        double nb = (double)NBC * (double)NBC;
        out[0] = (float)((t0 + t1 - 2.0 * p[2]) / nw);   // p2 = full st sum
        out[1] = (float)((t3 + t4 - 2.0 * p[5]) / nb);
    }
}

extern "C" void kernel_launch(void* const* d_in, const int* in_sizes, int n_in,
                              void* d_out, int out_size, void* d_ws, size_t ws_size,
                              hipStream_t stream) {
    const float* src = (const float*)d_in[0];
    const float* tgt = (const float*)d_in[1];
    float* out = (float*)d_out;
    float* ws = (float*)d_ws;

    static const double SIG[19] = {1e-06, 1e-05, 1e-04, 1e-03, 1e-02, 1e-01,
                                   1.0, 5.0, 10.0, 15.0, 20.0, 25.0, 30.0,
                                   35.0, 100.0, 1e3, 1e4, 1e5, 1e6};
    Coef co;
    for (int k = 0; k < 19; ++k)
        co.c[k] = (float)(-1.0 / (2.0 * SIG[k] * 0.6931471805599453));  // -log2e/(2s)

    compute_E<<<200, 256, 0, stream>>>(src, tgt, ws);
    scatter<<<27, 256, 0, stream>>>(ws);
    build_tab<<<8, 256, 0, stream>>>(ws, co);
    gk_persist<<<GK_GRID, 256, 0, stream>>>(ws, co);
    finalize<<<1, 64, 0, stream>>>(ws, out);
}

// Round 11
// 76.206 us; speedup vs baseline: 4.2993x; 4.2993x over previous
//
#include <hip/hip_runtime.h>

// ---------------------------------------------------------------------------
// MaximumMeanDiscrepancy: BATCH=160, INSTANCES=4, FEAT=1024, P=40
// out[0] = mmd(wcs, wct), out[1] = mmd(bcs, bct)
// ---------------------------------------------------------------------------

#define FEAT   1024
#define NROW   160     // BATCH
#define NBC    6088    // (1 + 39*39) * 4
#define NWC    160

// workspace layout (float offsets). bci/wci INTERLEAVED: row i = {src f4, tgt f4}.
// 256 pad rows of 1e19f follow each array (pad d -> clamps to zero top table
// cell -> contributes exactly 0, never hot). The global PL table (float2[2048])
// lives in the dead E_t region (E dead after scatter; build_tab runs after).
#define WS_ES   0          // E_s [160*160]
#define WS_ET   25600      // E_t [160*160]  (later: PL table float2[2048])
#define WS_TAB  25600
#define WS_BCI  51200      // bci [(6088+256)*8]
#define WS_WCI  101952     // wci [(160+256)*8]
#define WS_ACC_BYTES 421120  // 6*64 doubles
#define NSLOT  64

// PL table: sum of sigma in {20,25,30,35,100,1e3,1e4,1e5,1e6} over d in
// [2048, 2^27), 128 cells/octave, bits-indexed by (float_bits>>16)-17664.
// Cells with d >= ~2^25 evaluate to exact 0 by fp32 underflow, so the
// top-clamp (incl. 1e19 padding) contributes nothing and is never hot.
// hot (queue) threshold: cell t < 67  <=>  d < 3120.0f (sigma<=15 tier).
#define TAB_N    2048
#define TAB_BASE 17664     // bits(2048.f) >> 16
#define HOT_CELL 67

// persistent-block static item list, strided by grid (NO atomics):
//   [0, 12176)       bc pair-quarters: p = g>>2 rows {p,6087-p}, trip stride 4
//   [12176, 12256)   wc pairs {i, 159-i}
//   [12256, 12281)   st-diag strips (24 bc + 1 wc)
#define IT_BC_END 12176
#define IT_WC_END 12256
#define NITEMS    12281
#define GK_GRID   1536     // 6 blocks/CU x 256 CUs: all co-resident from t=0

struct Coef { float c[19]; };  // c[k] = -log2(e)/(2*sigma_k)  (exp2 form)

#if defined(__has_builtin)
#if __has_builtin(__builtin_amdgcn_exp2f)
#define EXP2(x) __builtin_amdgcn_exp2f(x)
#else
#define EXP2(x) exp2f(x)
#endif
#else
#define EXP2(x) exp2f(x)
#endif

// --- kernel 1: E[a,b] = ||f_a - f_b||^2 for both sides, 16x16 tiles ---------
__global__ __launch_bounds__(256) void compute_E(const float* __restrict__ Fs,
                                                 const float* __restrict__ Ft,
                                                 float* __restrict__ ws) {
    int side = blockIdx.x / 100;          // 0 = source, 1 = target
    int tile = blockIdx.x % 100;
    int trow = tile / 10, tcol = tile % 10;
    const float* F = side ? Ft : Fs;
    float* E = ws + (side ? WS_ET : WS_ES);

    __shared__ float As[16][132];
    __shared__ float Bs[16][132];
    int tid = threadIdx.x;
    int ti = tid >> 4, tj = tid & 15;
    int lr = tid >> 5;        // 0..7
    int lc4 = tid & 31;       // float4 column (0..31) of 128-dim chunk

    float acc = 0.f;
    for (int ch = 0; ch < 8; ++ch) {
        for (int rr = lr; rr < 16; rr += 8) {
            float4 a = *(const float4*)(F + (trow*16+rr)*FEAT + ch*128 + lc4*4);
            *(float4*)(&As[rr][lc4*4]) = a;
            float4 b = *(const float4*)(F + (tcol*16+rr)*FEAT + ch*128 + lc4*4);
            *(float4*)(&Bs[rr][lc4*4]) = b;
        }
        __syncthreads();
        #pragma unroll
        for (int c = 0; c < 128; c += 4) {
            float4 a = *(const float4*)(&As[ti][c]);
            float4 b = *(const float4*)(&Bs[tj][c]);
            float d0 = a.x - b.x, d1 = a.y - b.y, d2 = a.z - b.z, d3 = a.w - b.w;
            acc = fmaf(d0, d0, acc);
            acc = fmaf(d1, d1, acc);
            acc = fmaf(d2, d2, acc);
            acc = fmaf(d3, d3, acc);
        }
        __syncthreads();
    }
    E[(trow*16+ti)*NROW + tcol*16 + tj] = acc;
}

// --- kernel 2: gather interleaved bci/wci rows; pad; zero accumulators ------
__global__ __launch_bounds__(256) void scatter(float* __restrict__ ws) {
    int idx = blockIdx.x * blockDim.x + threadIdx.x;
    const float* E_s = ws + WS_ES;
    const float* E_t = ws + WS_ET;
    float4* bci = (float4*)(ws + WS_BCI);
    float4* wci = (float4*)(ws + WS_WCI);
    double* accs = (double*)((char*)ws + WS_ACC_BYTES);

    if (idx < 6 * NSLOT) accs[idx] = 0.0;

    if (idx < NBC) {
        int t = idx >> 2, ii = idx & 3;
        int pi, pj;
        if (t == 0) { pi = 0; pj = 1; }
        else {
            int tt = t - 1;
            pi = 1 + tt / 39;
            int jj = tt % 39;
            pj = (jj < pi) ? jj : jj + 1;
        }
        bci[2*idx]   = *(const float4*)(E_s + (4*pi + ii)*NROW + 4*pj);
        bci[2*idx+1] = *(const float4*)(E_t + (4*pi + ii)*NROW + 4*pj);
    } else if (idx < NBC + NWC) {
        int r = idx - NBC;
        int p = r >> 2;
        wci[2*r]   = *(const float4*)(E_s + r*NROW + 4*p);
        wci[2*r+1] = *(const float4*)(E_t + r*NROW + 4*p);
    } else if (idx < NBC + NWC + 256) {
        int p = NBC + (idx - (NBC + NWC));
        float4 pad = make_float4(1e19f, 1e19f, 1e19f, 1e19f);
        bci[2*p] = pad;
        bci[2*p+1] = pad;
    } else if (idx < NBC + NWC + 512) {
        int p = NWC + (idx - (NBC + NWC + 256));
        float4 pad = make_float4(1e19f, 1e19f, 1e19f, 1e19f);
        wci[2*p] = pad;
        wci[2*p+1] = pad;
    }
}

// --- exact term helpers ------------------------------------------------------
// Tier-skip is exact: exp2(d*c) == 0.0f once d*c <= -150:
// sigma<=35 -> d>=7279; sigma<=15 -> d>=3120; sigma<=1 -> 208.
__device__ __forceinline__ float tail_sum(float d, const Coef& co) {
    float s = EXP2(d * co.c[10]) + EXP2(d * co.c[11])
            + EXP2(d * co.c[12]) + EXP2(d * co.c[13]);   // 20,25,30,35
    if (d < 3120.0f)
        s += EXP2(d * co.c[7]) + EXP2(d * co.c[8]) + EXP2(d * co.c[9]); // 5,10,15
    if (d < 208.0f)
        s += EXP2(d * co.c[0]) + EXP2(d * co.c[1]) + EXP2(d * co.c[2])
           + EXP2(d * co.c[3]) + EXP2(d * co.c[4]) + EXP2(d * co.c[5])
           + EXP2(d * co.c[6]);                           // sigma <= 1
    return s;
}
// big-5: sigma = 100, 1e3, 1e4, 1e5, 1e6 (exact)
__device__ __forceinline__ float big5(float d, const Coef& co) {
    return EXP2(d * co.c[14]) + EXP2(d * co.c[15]) + EXP2(d * co.c[16])
         + EXP2(d * co.c[17]) + EXP2(d * co.c[18]);
}
// big-9 (table contents): sigma = 20..35, 100, 1e3..1e6
__device__ __forceinline__ float big9(float d, const Coef& co) {
    float s = 0.f;
    #pragma unroll
    for (int k = 10; k < 19; ++k) s += EXP2(d * co.c[k]);
    return s;
}

__device__ __forceinline__ float sqd(float4 a, float4 b) {
    float d0 = a.x - b.x, d1 = a.y - b.y, d2 = a.z - b.z, d3 = a.w - b.w;
    float d = d0 * d0;
    d = fmaf(d1, d1, d);
    d = fmaf(d2, d2, d);
    return fmaf(d3, d3, d);
}

// --- kernel 2b: build the global PL table (dead E_t region) -----------------
// midpoint-corrected chord per cell; cells never cross an exponent boundary.
__global__ __launch_bounds__(256) void build_tab(float* __restrict__ ws, Coef co) {
    int k = blockIdx.x * 256 + threadIdx.x;
    if (k >= TAB_N) return;
    unsigned u_lo = (unsigned)(TAB_BASE + k) << 16;
    float d_lo = __uint_as_float(u_lo);
    float d_mi = __uint_as_float(u_lo + 0x8000u);
    float d_hi = __uint_as_float(u_lo + 0x10000u);
    float f_lo = big9(d_lo, co), f_mi = big9(d_mi, co), f_hi = big9(d_hi, co);
    float2 e;
    e.x = f_lo + 0.5f * (f_mi - 0.5f * (f_lo + f_hi));
    e.y = (f_hi - f_lo) * (1.0f / 65536.0f);
    ((float2*)(ws + WS_TAB))[k] = e;
}

// --- kernel 3: persistent blocks, static round-robin items ------------------
// 1536 co-resident blocks; block b handles items b, b+1536, ... (NO atomics,
// NO in-loop barriers: item decode is a pure function of g; queues are
// per-wave). Per trip: 2 f4 loads, 4 sqd, 4 table lookups, zero inline exps.
// Hot pairs (cell<67, ~0.43%/eval) -> 3 per-wave LDS queues under one __any
// per trip; drain adds big5+tail-tab(d) so the inline lookup cancels exactly.
// Queues hold one class (bc jobs 3..5 first, then wc jobs 0..2) — flushed at
// the per-wave class transition.
__global__ __launch_bounds__(256, 6) void gk_pers(float* __restrict__ ws, Coef co) {
    const float4* bci = (const float4*)(ws + WS_BCI);
    const float4* wci = (const float4*)(ws + WS_WCI);
    double* accs = (double*)((char*)ws + WS_ACC_BYTES);

    __shared__ float2 tabs[TAB_N];
    __shared__ float qb[4][3][128];
    __shared__ double wsum[4][6];

    int tid = threadIdx.x;
    int lane = tid & 63, w = tid >> 6;

    {   // copy PL table global -> LDS (4 x float4 per thread)
        const float4* tg = (const float4*)(ws + WS_TAB);
        float4* td = (float4*)tabs;
        for (int k = tid; k < TAB_N / 2; k += 256) td[k] = tg[k];
    }
    __syncthreads();

    auto tab_get = [&](float d) -> float {
        unsigned u = __float_as_uint(d);
        int t = (int)(u >> 16) - TAB_BASE;
        t = min(max(t, 0), TAB_N - 1);
        float2 e = tabs[t];
        return fmaf((float)(u & 0xFFFFu), e.y, e.x);
    };
    auto drain_term = [&](float d) -> float {
        return big5(d, co) + tail_sum(d, co) - tab_get(d);
    };

    int qn0 = 0, qn1 = 0, qn2 = 0;
    double a0 = 0.0, a1 = 0.0, a2 = 0.0, a3 = 0.0, a4 = 0.0, a5 = 0.0;

#define MBCNT(m) __builtin_amdgcn_mbcnt_hi((unsigned)((m) >> 32), \
                  __builtin_amdgcn_mbcnt_lo((unsigned)(m), 0u))
#define PUSHQ(Q, QN, dv, h) { unsigned long long m_ = __ballot(h); \
        if (h) qb[w][Q][(QN) + MBCNT(m_)] = (dv); \
        (QN) += (int)__popcll(m_); }

    auto flush3 = [&](double& A0, double& A1, double& A2) {
        if (lane < qn0) A0 += (double)drain_term(qb[w][0][lane]);
        if (lane < qn1) A1 += (double)drain_term(qb[w][1][lane]);
        if (lane < qn2) A2 += (double)drain_term(qb[w][2][lane]);
        qn0 = qn1 = qn2 = 0;
    };

    auto process = [&](const float4* __restrict__ Yv, int N, int i,
                       int par, int S, double& A0, double& A1, double& A2) {
        int T = (N - i - 1 + 255) >> 8;
        int trips = (T - par + S - 1) / S;
        if (trips <= 0) return;
        float4 xs = Yv[2*i], xt = Yv[2*i+1];
        const float4* Yp = Yv + 2*((i + 1) + par*256 + tid);
        int stride = 512 * S;
        float m0 = 0.f, m1 = 0.f, m2 = 0.f;
        for (int t = 0; t < trips; ++t) {
            float4 ys = Yp[0], yt = Yp[1];
            Yp += stride;
            float dss = sqd(xs, ys), dtt = sqd(xt, yt);
            float dst = sqd(xs, yt), dts = sqd(xt, ys);
            unsigned u0 = __float_as_uint(dss), u1 = __float_as_uint(dtt);
            unsigned u2 = __float_as_uint(dst), u3 = __float_as_uint(dts);
            int t0 = (int)(u0 >> 16) - TAB_BASE, t1 = (int)(u1 >> 16) - TAB_BASE;
            int t2 = (int)(u2 >> 16) - TAB_BASE, t3 = (int)(u3 >> 16) - TAB_BASE;
            bool h0 = t0 < HOT_CELL, h1 = t1 < HOT_CELL;
            bool h2 = t2 < HOT_CELL, h3 = t3 < HOT_CELL;
            t0 = min(max(t0, 0), TAB_N - 1);
            t1 = min(max(t1, 0), TAB_N - 1);
            t2 = min(max(t2, 0), TAB_N - 1);
            t3 = min(max(t3, 0), TAB_N - 1);
            float2 e0 = tabs[t0], e1 = tabs[t1], e2 = tabs[t2], e3 = tabs[t3];
            m0 += fmaf((float)(u0 & 0xFFFFu), e0.y, e0.x);
            m1 += fmaf((float)(u1 & 0xFFFFu), e1.y, e1.x);
            m2 += fmaf((float)(u2 & 0xFFFFu), e2.y, e2.x)
                + fmaf((float)(u3 & 0xFFFFu), e3.y, e3.x);
            if (__any(h0 | h1 | h2 | h3)) {
                PUSHQ(0, qn0, dss, h0);
                if (qn0 >= 64) { qn0 -= 64; m0 += drain_term(qb[w][0][qn0 + lane]); }
                PUSHQ(1, qn1, dtt, h1);
                if (qn1 >= 64) { qn1 -= 64; m1 += drain_term(qb[w][1][qn1 + lane]); }
                PUSHQ(2, qn2, dst, h2);
                if (qn2 >= 64) { qn2 -= 64; m2 += drain_term(qb[w][2][qn2 + lane]); }
                PUSHQ(2, qn2, dts, h3);
                if (qn2 >= 64) { qn2 -= 64; m2 += drain_term(qb[w][2][qn2 + lane]); }
            }
        }
        A0 += (double)m0; A1 += (double)m1; A2 += (double)m2;
    };

    int qbc = 1;   // queues currently hold bc-class entries
    for (int g = blockIdx.x; g < NITEMS; g += GK_GRID) {
        if (g < IT_BC_END) {                   // bc pair-quarter
            int p = g >> 2, oc = g & 3;
            process(bci, NBC, p,        oc, 4, a3, a4, a5);
            process(bci, NBC, 6087 - p, oc, 4, a3, a4, a5);
        } else {
            if (qbc) { flush3(a3, a4, a5); qbc = 0; }
            if (g < IT_WC_END) {               // wc pair
                int i = g - IT_BC_END;
                process(wci, NWC, i,       0, 1, a0, a1, a2);
                process(wci, NWC, 159 - i, 0, 1, a0, a1, a2);
            } else {                           // st-diag strips (exact path)
                int s = g - IT_WC_END;
                if (s < 24) {
                    int i0 = s * 256 + tid;
                    if (i0 < NBC) {
                        float d = sqd(bci[2*i0], bci[2*i0+1]);
                        float sv = big5(d, co);
                        if (d < 7280.0f) sv += tail_sum(d, co);
                        a5 += (double)sv;
                    }
                } else {
                    if (tid < NWC) {
                        float d = sqd(wci[2*tid], wci[2*tid+1]);
                        float sv = big5(d, co);
                        if (d < 7280.0f) sv += tail_sum(d, co);
                        a2 += (double)sv;
                    }
                }
            }
        }
    }
    if (qbc) flush3(a3, a4, a5); else flush3(a0, a1, a2);

    // wave reduce, then block reduce 4 waves, 6 jobs
    #pragma unroll
    for (int off = 32; off; off >>= 1) {
        a0 += __shfl_down(a0, off, 64);
        a1 += __shfl_down(a1, off, 64);
        a2 += __shfl_down(a2, off, 64);
        a3 += __shfl_down(a3, off, 64);
        a4 += __shfl_down(a4, off, 64);
        a5 += __shfl_down(a5, off, 64);
    }
    if (lane == 0) {
        wsum[w][0] = a0; wsum[w][1] = a1; wsum[w][2] = a2;
        wsum[w][3] = a3; wsum[w][4] = a4; wsum[w][5] = a5;
    }
    __syncthreads();
    if (tid < 6) {
        double tot = wsum[0][tid] + wsum[1][tid] + wsum[2][tid] + wsum[3][tid];
        atomicAdd(&accs[tid * NSLOT + (blockIdx.x & (NSLOT - 1))], tot);
    }
#undef PUSHQ
#undef MBCNT
}

// --- kernel 4: combine into the two output scalars --------------------------
__global__ void finalize(const float* __restrict__ ws, float* __restrict__ out) {
    const double* accs = (const double*)((const char*)ws + WS_ACC_BYTES);
    int lane = threadIdx.x;  // blockDim = 64
    double p[6];
    #pragma unroll
    for (int q = 0; q < 6; ++q) {
        p[q] = accs[q * NSLOT + lane];
        #pragma unroll
        for (int off = 32; off; off >>= 1) p[q] += __shfl_down(p[q], off, 64);
    }
    if (lane == 0) {
        double t0 = 2.0 * p[0] + 19.0 * NWC;   // self: 2*triangle + diag
        double t1 = 2.0 * p[1] + 19.0 * NWC;
        double t3 = 2.0 * p[3] + 19.0 * NBC;
        double t4 = 2.0 * p[4] + 19.0 * NBC;
        double nw = (double)NWC * (double)NWC;
        double nb = (double)NBC * (double)NBC;
        out[0] = (float)((t0 + t1 - 2.0 * p[2]) / nw);   // p2 = full st sum
        out[1] = (float)((t3 + t4 - 2.0 * p[5]) / nb);
    }
}

extern "C" void kernel_launch(void* const* d_in, const int* in_sizes, int n_in,
                              void* d_out, int out_size, void* d_ws, size_t ws_size,
                              hipStream_t stream) {
    const float* src = (const float*)d_in[0];
    const float* tgt = (const float*)d_in[1];
    float* out = (float*)d_out;
    float* ws = (float*)d_ws;

    static const double SIG[19] = {1e-06, 1e-05, 1e-04, 1e-03, 1e-02, 1e-01,
                                   1.0, 5.0, 10.0, 15.0, 20.0, 25.0, 30.0,
                                   35.0, 100.0, 1e3, 1e4, 1e5, 1e6};
    Coef co;
    for (int k = 0; k < 19; ++k)
        co.c[k] = (float)(-1.0 / (2.0 * SIG[k] * 0.6931471805599453));  // -log2e/(2s)

    compute_E<<<200, 256, 0, stream>>>(src, tgt, ws);
    scatter<<<27, 256, 0, stream>>>(ws);
    build_tab<<<8, 256, 0, stream>>>(ws, co);
    gk_pers<<<GK_GRID, 256, 0, stream>>>(ws, co);
    finalize<<<1, 64, 0, stream>>>(ws, out);
}

// Round 12
// 72.468 us; speedup vs baseline: 4.5211x; 1.0516x over previous
//
#include <hip/hip_runtime.h>

// ---------------------------------------------------------------------------
// MaximumMeanDiscrepancy: BATCH=160, INSTANCES=4, FEAT=1024, P=40
// out[0] = mmd(wcs, wct), out[1] = mmd(bcs, bct)
// ---------------------------------------------------------------------------

#define FEAT   1024
#define NROW   160     // BATCH
#define NBC    6088    // (1 + 39*39) * 4
#define NWC    160

// workspace layout (float offsets). bci/wci INTERLEAVED: row i = {src f4, tgt f4}.
// 256 pad rows of 1e19f follow each array (pad d -> clamps to zero top table
// cell -> contributes exactly 0, never hot). The global PL table (float2[2048])
// lives in the dead E_t region (E dead after scatter; build_tab runs after).
#define WS_ES   0          // E_s [160*160]
#define WS_ET   25600      // E_t [160*160]  (later: PL table float2[2048])
#define WS_TAB  25600
#define WS_BCI  51200      // bci [(6088+256)*8]
#define WS_WCI  101952     // wci [(160+256)*8]
#define WS_ACC_BYTES 421120  // 6*64 doubles
#define NSLOT  64

// PL table: sum of sigma in {20,25,30,35,100,1e3,1e4,1e5,1e6} over d in
// [2048, 2^27), 128 cells/octave, bits-indexed by (float_bits>>16)-17664.
// Cells with d >= ~2^25 evaluate to exact 0 by fp32 underflow, so the
// top-clamp (incl. 1e19 padding) contributes nothing and is never hot.
// hot (queue) threshold: cell t < 67  <=>  d < 3120.0f (sigma<=15 tier).
#define TAB_N    2048
#define TAB_BASE 17664     // bits(2048.f) >> 16
#define HOT_CELL 67

// persistent-block static item list, strided by grid (NO atomics):
//   [0, 12176)       bc pair-quarters: p = g>>2 rows {p,6087-p};
//                    quarter-phase oc = (g + k) & 3 cycles PER BLOCK (k = item
//                    ordinal) — bijective since 1536 ≡ 0 mod 4 keeps the four
//                    g of a pair in one k; fixes the oc-class imbalance.
//   [12176, 12256)   wc pairs {i, 159-i}
//   [12256, 12281)   st-diag strips (24 bc + 1 wc)
#define IT_BC_END 12176
#define IT_WC_END 12256
#define NITEMS    12281
#define GK_GRID   1536     // 6 blocks/CU x 256 CUs: all co-resident from t=0

struct Coef { float c[19]; };  // c[k] = -log2(e)/(2*sigma_k)  (exp2 form)

#if defined(__has_builtin)
#if __has_builtin(__builtin_amdgcn_exp2f)
#define EXP2(x) __builtin_amdgcn_exp2f(x)
#else
#define EXP2(x) exp2f(x)
#endif
#else
#define EXP2(x) exp2f(x)
#endif

// --- kernel 1: E[a,b] = ||f_a - f_b||^2 for both sides, 16x16 tiles ---------
__global__ __launch_bounds__(256) void compute_E(const float* __restrict__ Fs,
                                                 const float* __restrict__ Ft,
                                                 float* __restrict__ ws) {
    int side = blockIdx.x / 100;          // 0 = source, 1 = target
    int tile = blockIdx.x % 100;
    int trow = tile / 10, tcol = tile % 10;
    const float* F = side ? Ft : Fs;
    float* E = ws + (side ? WS_ET : WS_ES);

    __shared__ float As[16][132];
    __shared__ float Bs[16][132];
    int tid = threadIdx.x;
    int ti = tid >> 4, tj = tid & 15;
    int lr = tid >> 5;        // 0..7
    int lc4 = tid & 31;       // float4 column (0..31) of 128-dim chunk

    float acc = 0.f;
    for (int ch = 0; ch < 8; ++ch) {
        for (int rr = lr; rr < 16; rr += 8) {
            float4 a = *(const float4*)(F + (trow*16+rr)*FEAT + ch*128 + lc4*4);
            *(float4*)(&As[rr][lc4*4]) = a;
            float4 b = *(const float4*)(F + (tcol*16+rr)*FEAT + ch*128 + lc4*4);
            *(float4*)(&Bs[rr][lc4*4]) = b;
        }
        __syncthreads();
        #pragma unroll
        for (int c = 0; c < 128; c += 4) {
            float4 a = *(const float4*)(&As[ti][c]);
            float4 b = *(const float4*)(&Bs[tj][c]);
            float d0 = a.x - b.x, d1 = a.y - b.y, d2 = a.z - b.z, d3 = a.w - b.w;
            acc = fmaf(d0, d0, acc);
            acc = fmaf(d1, d1, acc);
            acc = fmaf(d2, d2, acc);
            acc = fmaf(d3, d3, acc);
        }
        __syncthreads();
    }
    E[(trow*16+ti)*NROW + tcol*16 + tj] = acc;
}

// --- kernel 2: gather interleaved bci/wci rows; pad; zero accumulators ------
__global__ __launch_bounds__(256) void scatter(float* __restrict__ ws) {
    int idx = blockIdx.x * blockDim.x + threadIdx.x;
    const float* E_s = ws + WS_ES;
    const float* E_t = ws + WS_ET;
    float4* bci = (float4*)(ws + WS_BCI);
    float4* wci = (float4*)(ws + WS_WCI);
    double* accs = (double*)((char*)ws + WS_ACC_BYTES);

    if (idx < 6 * NSLOT) accs[idx] = 0.0;

    if (idx < NBC) {
        int t = idx >> 2, ii = idx & 3;
        int pi, pj;
        if (t == 0) { pi = 0; pj = 1; }
        else {
            int tt = t - 1;
            pi = 1 + tt / 39;
            int jj = tt % 39;
            pj = (jj < pi) ? jj : jj + 1;
        }
        bci[2*idx]   = *(const float4*)(E_s + (4*pi + ii)*NROW + 4*pj);
        bci[2*idx+1] = *(const float4*)(E_t + (4*pi + ii)*NROW + 4*pj);
    } else if (idx < NBC + NWC) {
        int r = idx - NBC;
        int p = r >> 2;
        wci[2*r]   = *(const float4*)(E_s + r*NROW + 4*p);
        wci[2*r+1] = *(const float4*)(E_t + r*NROW + 4*p);
    } else if (idx < NBC + NWC + 256) {
        int p = NBC + (idx - (NBC + NWC));
        float4 pad = make_float4(1e19f, 1e19f, 1e19f, 1e19f);
        bci[2*p] = pad;
        bci[2*p+1] = pad;
    } else if (idx < NBC + NWC + 512) {
        int p = NWC + (idx - (NBC + NWC + 256));
        float4 pad = make_float4(1e19f, 1e19f, 1e19f, 1e19f);
        wci[2*p] = pad;
        wci[2*p+1] = pad;
    }
}

// --- exact term helpers ------------------------------------------------------
// Tier-skip is exact: exp2(d*c) == 0.0f once d*c <= -150:
// sigma<=35 -> d>=7279; sigma<=15 -> d>=3120; sigma<=1 -> 208.
__device__ __forceinline__ float tail_sum(float d, const Coef& co) {
    float s = EXP2(d * co.c[10]) + EXP2(d * co.c[11])
            + EXP2(d * co.c[12]) + EXP2(d * co.c[13]);   // 20,25,30,35
    if (d < 3120.0f)
        s += EXP2(d * co.c[7]) + EXP2(d * co.c[8]) + EXP2(d * co.c[9]); // 5,10,15
    if (d < 208.0f)
        s += EXP2(d * co.c[0]) + EXP2(d * co.c[1]) + EXP2(d * co.c[2])
           + EXP2(d * co.c[3]) + EXP2(d * co.c[4]) + EXP2(d * co.c[5])
           + EXP2(d * co.c[6]);                           // sigma <= 1
    return s;
}
// big-5: sigma = 100, 1e3, 1e4, 1e5, 1e6 (exact)
__device__ __forceinline__ float big5(float d, const Coef& co) {
    return EXP2(d * co.c[14]) + EXP2(d * co.c[15]) + EXP2(d * co.c[16])
         + EXP2(d * co.c[17]) + EXP2(d * co.c[18]);
}
// big-9 (table contents): sigma = 20..35, 100, 1e3..1e6
__device__ __forceinline__ float big9(float d, const Coef& co) {
    float s = 0.f;
    #pragma unroll
    for (int k = 10; k < 19; ++k) s += EXP2(d * co.c[k]);
    return s;
}

__device__ __forceinline__ float sqd(float4 a, float4 b) {
    float d0 = a.x - b.x, d1 = a.y - b.y, d2 = a.z - b.z, d3 = a.w - b.w;
    float d = d0 * d0;
    d = fmaf(d1, d1, d);
    d = fmaf(d2, d2, d);
    return fmaf(d3, d3, d);
}

// --- kernel 2b: build the global PL table (dead E_t region) -----------------
// midpoint-corrected chord per cell; cells never cross an exponent boundary.
__global__ __launch_bounds__(256) void build_tab(float* __restrict__ ws, Coef co) {
    int k = blockIdx.x * 256 + threadIdx.x;
    if (k >= TAB_N) return;
    unsigned u_lo = (unsigned)(TAB_BASE + k) << 16;
    float d_lo = __uint_as_float(u_lo);
    float d_mi = __uint_as_float(u_lo + 0x8000u);
    float d_hi = __uint_as_float(u_lo + 0x10000u);
    float f_lo = big9(d_lo, co), f_mi = big9(d_mi, co), f_hi = big9(d_hi, co);
    float2 e;
    e.x = f_lo + 0.5f * (f_mi - 0.5f * (f_lo + f_hi));
    e.y = (f_hi - f_lo) * (1.0f / 65536.0f);
    ((float2*)(ws + WS_TAB))[k] = e;
}

// --- kernel 3: persistent blocks, static round-robin items ------------------
// 1536 co-resident blocks; block b handles items b, b+1536, ... (NO atomics,
// NO in-loop barriers). Quarter-phase oc cycles per block via (g + k) & 3 so
// every block gets a balanced mix of long/short quarters. Per trip: 2 f4
// loads, 4 sqd, 4 table lookups, zero inline exps. Hot pairs (cell<67,
// ~0.43%/eval) -> 3 per-wave LDS queues under one __any per trip; drain adds
// big5+tail-tab(d) so the inline lookup cancels exactly. Queues hold one
// class (bc first, then wc) — flushed at the per-wave class transition.
__global__ __launch_bounds__(256, 6) void gk_pers(float* __restrict__ ws, Coef co) {
    const float4* bci = (const float4*)(ws + WS_BCI);
    const float4* wci = (const float4*)(ws + WS_WCI);
    double* accs = (double*)((char*)ws + WS_ACC_BYTES);

    __shared__ float2 tabs[TAB_N];
    __shared__ float qb[4][3][128];
    __shared__ double wsum[4][6];

    int tid = threadIdx.x;
    int lane = tid & 63, w = tid >> 6;

    {   // copy PL table global -> LDS (4 x float4 per thread)
        const float4* tg = (const float4*)(ws + WS_TAB);
        float4* td = (float4*)tabs;
        for (int k = tid; k < TAB_N / 2; k += 256) td[k] = tg[k];
    }
    __syncthreads();

    auto tab_get = [&](float d) -> float {
        unsigned u = __float_as_uint(d);
        int t = (int)(u >> 16) - TAB_BASE;
        t = min(max(t, 0), TAB_N - 1);
        float2 e = tabs[t];
        return fmaf((float)(u & 0xFFFFu), e.y, e.x);
    };
    auto drain_term = [&](float d) -> float {
        return big5(d, co) + tail_sum(d, co) - tab_get(d);
    };

    int qn0 = 0, qn1 = 0, qn2 = 0;
    double a0 = 0.0, a1 = 0.0, a2 = 0.0, a3 = 0.0, a4 = 0.0, a5 = 0.0;

#define MBCNT(m) __builtin_amdgcn_mbcnt_hi((unsigned)((m) >> 32), \
                  __builtin_amdgcn_mbcnt_lo((unsigned)(m), 0u))
#define PUSHQ(Q, QN, dv, h) { unsigned long long m_ = __ballot(h); \
        if (h) qb[w][Q][(QN) + MBCNT(m_)] = (dv); \
        (QN) += (int)__popcll(m_); }

    auto flush3 = [&](double& A0, double& A1, double& A2) {
        if (lane < qn0) A0 += (double)drain_term(qb[w][0][lane]);
        if (lane < qn1) A1 += (double)drain_term(qb[w][1][lane]);
        if (lane < qn2) A2 += (double)drain_term(qb[w][2][lane]);
        qn0 = qn1 = qn2 = 0;
    };

    auto process = [&](const float4* __restrict__ Yv, int N, int i,
                       int par, int S, double& A0, double& A1, double& A2) {
        int T = (N - i - 1 + 255) >> 8;
        int trips = (T - par + S - 1) / S;
        if (trips <= 0) return;
        float4 xs = Yv[2*i], xt = Yv[2*i+1];
        const float4* Yp = Yv + 2*((i + 1) + par*256 + tid);
        int stride = 512 * S;
        float m0 = 0.f, m1 = 0.f, m2 = 0.f;
        for (int t = 0; t < trips; ++t) {
            float4 ys = Yp[0], yt = Yp[1];
            Yp += stride;
            float dss = sqd(xs, ys), dtt = sqd(xt, yt);
            float dst = sqd(xs, yt), dts = sqd(xt, ys);
            unsigned u0 = __float_as_uint(dss), u1 = __float_as_uint(dtt);
            unsigned u2 = __float_as_uint(dst), u3 = __float_as_uint(dts);
            int t0 = (int)(u0 >> 16) - TAB_BASE, t1 = (int)(u1 >> 16) - TAB_BASE;
            int t2 = (int)(u2 >> 16) - TAB_BASE, t3 = (int)(u3 >> 16) - TAB_BASE;
            bool h0 = t0 < HOT_CELL, h1 = t1 < HOT_CELL;
            bool h2 = t2 < HOT_CELL, h3 = t3 < HOT_CELL;
            t0 = min(max(t0, 0), TAB_N - 1);
            t1 = min(max(t1, 0), TAB_N - 1);
            t2 = min(max(t2, 0), TAB_N - 1);
            t3 = min(max(t3, 0), TAB_N - 1);
            float2 e0 = tabs[t0], e1 = tabs[t1], e2 = tabs[t2], e3 = tabs[t3];
            m0 += fmaf((float)(u0 & 0xFFFFu), e0.y, e0.x);
            m1 += fmaf((float)(u1 & 0xFFFFu), e1.y, e1.x);
            m2 += fmaf((float)(u2 & 0xFFFFu), e2.y, e2.x)
                + fmaf((float)(u3 & 0xFFFFu), e3.y, e3.x);
            if (__any(h0 | h1 | h2 | h3)) {
                PUSHQ(0, qn0, dss, h0);
                if (qn0 >= 64) { qn0 -= 64; m0 += drain_term(qb[w][0][qn0 + lane]); }
                PUSHQ(1, qn1, dtt, h1);
                if (qn1 >= 64) { qn1 -= 64; m1 += drain_term(qb[w][1][qn1 + lane]); }
                PUSHQ(2, qn2, dst, h2);
                if (qn2 >= 64) { qn2 -= 64; m2 += drain_term(qb[w][2][qn2 + lane]); }
                PUSHQ(2, qn2, dts, h3);
                if (qn2 >= 64) { qn2 -= 64; m2 += drain_term(qb[w][2][qn2 + lane]); }
            }
        }
        A0 += (double)m0; A1 += (double)m1; A2 += (double)m2;
    };

    int qbc = 1;   // queues currently hold bc-class entries
    int k = 0;     // per-block item ordinal (cycles the quarter phase)
    for (int g = blockIdx.x; g < NITEMS; g += GK_GRID, ++k) {
        if (g < IT_BC_END) {                   // bc pair-quarter, cycled phase
            int p = g >> 2, oc = (g + k) & 3;
            process(bci, NBC, p,        oc, 4, a3, a4, a5);
            process(bci, NBC, 6087 - p, oc, 4, a3, a4, a5);
        } else {
            if (qbc) { flush3(a3, a4, a5); qbc = 0; }
            if (g < IT_WC_END) {               // wc pair
                int i = g - IT_BC_END;
                process(wci, NWC, i,       0, 1, a0, a1, a2);
                process(wci, NWC, 159 - i, 0, 1, a0, a1, a2);
            } else {                           // st-diag strips (exact path)
                int s = g - IT_WC_END;
                if (s < 24) {
                    int i0 = s * 256 + tid;
                    if (i0 < NBC) {
                        float d = sqd(bci[2*i0], bci[2*i0+1]);
                        float sv = big5(d, co);
                        if (d < 7280.0f) sv += tail_sum(d, co);
                        a5 += (double)sv;
                    }
                } else {
                    if (tid < NWC) {
                        float d = sqd(wci[2*tid], wci[2*tid+1]);
                        float sv = big5(d, co);
                        if (d < 7280.0f) sv += tail_sum(d, co);
                        a2 += (double)sv;
                    }
                }
            }
        }
    }
    if (qbc) flush3(a3, a4, a5); else flush3(a0, a1, a2);

    // wave reduce, then block reduce 4 waves, 6 jobs
    #pragma unroll
    for (int off = 32; off; off >>= 1) {
        a0 += __shfl_down(a0, off, 64);
        a1 += __shfl_down(a1, off, 64);
        a2 += __shfl_down(a2, off, 64);
        a3 += __shfl_down(a3, off, 64);
        a4 += __shfl_down(a4, off, 64);
        a5 += __shfl_down(a5, off, 64);
    }
    if (lane == 0) {
        wsum[w][0] = a0; wsum[w][1] = a1; wsum[w][2] = a2;
        wsum[w][3] = a3; wsum[w][4] = a4; wsum[w][5] = a5;
    }
    __syncthreads();
    if (tid < 6) {
        double tot = wsum[0][tid] + wsum[1][tid] + wsum[2][tid] + wsum[3][tid];
        atomicAdd(&accs[tid * NSLOT + (blockIdx.x & (NSLOT - 1))], tot);
    }
#undef PUSHQ
#undef MBCNT
}

// --- kernel 4: combine into the two output scalars --------------------------
__global__ void finalize(const float* __restrict__ ws, float* __restrict__ out) {
    const double* accs = (const double*)((const char*)ws + WS_ACC_BYTES);
    int lane = threadIdx.x;  // blockDim = 64
    double p[6];
    #pragma unroll
    for (int q = 0; q < 6; ++q) {
        p[q] = accs[q * NSLOT + lane];
        #pragma unroll
        for (int off = 32; off; off >>= 1) p[q] += __shfl_down(p[q], off, 64);
    }
    if (lane == 0) {
        double t0 = 2.0 * p[0] + 19.0 * NWC;   // self: 2*triangle + diag
        double t1 = 2.0 * p[1] + 19.0 * NWC;
        double t3 = 2.0 * p[3] + 19.0 * NBC;
        double t4 = 2.0 * p[4] + 19.0 * NBC;
        double nw = (double)NWC * (double)NWC;
        double nb = (double)NBC * (double)NBC;
        out[0] = (float)((t0 + t1 - 2.0 * p[2]) / nw);   // p2 = full st sum
        out[1] = (float)((t3 + t4 - 2.0 * p[5]) / nb);
    }
}

extern "C" void kernel_launch(void* const* d_in, const int* in_sizes, int n_in,
                              void* d_out, int out_size, void* d_ws, size_t ws_size,
                              hipStream_t stream) {
    const float* src = (const float*)d_in[0];
    const float* tgt = (const float*)d_in[1];
    float* out = (float*)d_out;
    float* ws = (float*)d_ws;

    static const double SIG[19] = {1e-06, 1e-05, 1e-04, 1e-03, 1e-02, 1e-01,
                                   1.0, 5.0, 10.0, 15.0, 20.0, 25.0, 30.0,
                                   35.0, 100.0, 1e3, 1e4, 1e5, 1e6};
    Coef co;
    for (int k = 0; k < 19; ++k)
        co.c[k] = (float)(-1.0 / (2.0 * SIG[k] * 0.6931471805599453));  // -log2e/(2s)

    compute_E<<<200, 256, 0, stream>>>(src, tgt, ws);
    scatter<<<27, 256, 0, stream>>>(ws);
    build_tab<<<8, 256, 0, stream>>>(ws, co);
    gk_pers<<<GK_GRID, 256, 0, stream>>>(ws, co);
    finalize<<<1, 64, 0, stream>>>(ws, out);
}

// Round 13
// 68.583 us; speedup vs baseline: 4.7772x; 1.0566x over previous
//
#include <hip/hip_runtime.h>

// ---------------------------------------------------------------------------
// MaximumMeanDiscrepancy: BATCH=160, INSTANCES=4, FEAT=1024, P=40
// out[0] = mmd(wcs, wct), out[1] = mmd(bcs, bct)
// ---------------------------------------------------------------------------

#define FEAT   1024
#define NROW   160     // BATCH
#define NBC    6088    // (1 + 39*39) * 4
#define NWC    160

// workspace layout (float offsets). bci/wci INTERLEAVED: row i = {src f4, tgt f4}.
// 256 pad rows of 1e19f follow each array (pad d -> clamps to top table cell
// ~1e-7 -> negligible). Global PL table (float2[2816]) lives in the dead E_t
// region (E dead after scatter; build_tab runs after).
#define WS_ES   0          // E_s [160*160]
#define WS_ET   25600      // E_t [160*160]  (later: PL table float2[2816])
#define WS_TAB  25600
#define WS_BCI  51200      // bci [(6088+256)*8]
#define WS_WCI  101952     // wci [(160+256)*8]
#define WS_ACC_BYTES 421120  // 6*64 doubles
#define NSLOT  64

// Full-range PL table: S(d) = sum over sigma in {1,5,10,15,20,25,30,35,100,
// 1e3,1e4,1e5,1e6} of exp2(d*c_sigma), d in [8, 2^25), 128 cells/octave,
// bits-indexed by (float_bits>>16) - 16640. sigma <= 0.1 is < 4e-18 for d>=8
// (vanishes exactly in f32 addition). d < 8 clamps to cell 0 (P ~ 1e-8);
// d >= 2^25 clamps to the top cell (~1e-7). Midpoint-corrected chord per
// cell: |err| <= ~3e-6 per eval in the multi-sigma curvature zone.
#define TAB_N    2816
#define TAB_BASE 16640     // bits(8.0f) >> 16

// deep-queue grid: single-class blocks, ~6 trips each
//   [0, 12176)       bc quarter-pairs: p = b>>2 rows {p,6087-p}, phase b&3
//   [12176, 12256)   wc pairs {i, 159-i}
//   [12256, 12281)   st-diag strips (24 bc + 1 wc)
#define IT_BC_END 12176
#define IT_WC_END 12256
#define GK_GRID   12281

struct Coef { float c[19]; };  // c[k] = -log2(e)/(2*sigma_k)  (exp2 form)

#if defined(__has_builtin)
#if __has_builtin(__builtin_amdgcn_exp2f)
#define EXP2(x) __builtin_amdgcn_exp2f(x)
#else
#define EXP2(x) exp2f(x)
#endif
#else
#define EXP2(x) exp2f(x)
#endif

// --- kernel 1: E[a,b] = ||f_a - f_b||^2 for both sides, 16x16 tiles ---------
__global__ __launch_bounds__(256) void compute_E(const float* __restrict__ Fs,
                                                 const float* __restrict__ Ft,
                                                 float* __restrict__ ws) {
    int side = blockIdx.x / 100;          // 0 = source, 1 = target
    int tile = blockIdx.x % 100;
    int trow = tile / 10, tcol = tile % 10;
    const float* F = side ? Ft : Fs;
    float* E = ws + (side ? WS_ET : WS_ES);

    __shared__ float As[16][132];
    __shared__ float Bs[16][132];
    int tid = threadIdx.x;
    int ti = tid >> 4, tj = tid & 15;
    int lr = tid >> 5;        // 0..7
    int lc4 = tid & 31;       // float4 column (0..31) of 128-dim chunk

    float acc = 0.f;
    for (int ch = 0; ch < 8; ++ch) {
        for (int rr = lr; rr < 16; rr += 8) {
            float4 a = *(const float4*)(F + (trow*16+rr)*FEAT + ch*128 + lc4*4);
            *(float4*)(&As[rr][lc4*4]) = a;
            float4 b = *(const float4*)(F + (tcol*16+rr)*FEAT + ch*128 + lc4*4);
            *(float4*)(&Bs[rr][lc4*4]) = b;
        }
        __syncthreads();
        #pragma unroll
        for (int c = 0; c < 128; c += 4) {
            float4 a = *(const float4*)(&As[ti][c]);
            float4 b = *(const float4*)(&Bs[tj][c]);
            float d0 = a.x - b.x, d1 = a.y - b.y, d2 = a.z - b.z, d3 = a.w - b.w;
            acc = fmaf(d0, d0, acc);
            acc = fmaf(d1, d1, acc);
            acc = fmaf(d2, d2, acc);
            acc = fmaf(d3, d3, acc);
        }
        __syncthreads();
    }
    E[(trow*16+ti)*NROW + tcol*16 + tj] = acc;
}

// --- kernel 2: gather interleaved bci/wci rows; pad; zero accumulators ------
__global__ __launch_bounds__(256) void scatter(float* __restrict__ ws) {
    int idx = blockIdx.x * blockDim.x + threadIdx.x;
    const float* E_s = ws + WS_ES;
    const float* E_t = ws + WS_ET;
    float4* bci = (float4*)(ws + WS_BCI);
    float4* wci = (float4*)(ws + WS_WCI);
    double* accs = (double*)((char*)ws + WS_ACC_BYTES);

    if (idx < 6 * NSLOT) accs[idx] = 0.0;

    if (idx < NBC) {
        int t = idx >> 2, ii = idx & 3;
        int pi, pj;
        if (t == 0) { pi = 0; pj = 1; }
        else {
            int tt = t - 1;
            pi = 1 + tt / 39;
            int jj = tt % 39;
            pj = (jj < pi) ? jj : jj + 1;
        }
        bci[2*idx]   = *(const float4*)(E_s + (4*pi + ii)*NROW + 4*pj);
        bci[2*idx+1] = *(const float4*)(E_t + (4*pi + ii)*NROW + 4*pj);
    } else if (idx < NBC + NWC) {
        int r = idx - NBC;
        int p = r >> 2;
        wci[2*r]   = *(const float4*)(E_s + r*NROW + 4*p);
        wci[2*r+1] = *(const float4*)(E_t + r*NROW + 4*p);
    } else if (idx < NBC + NWC + 256) {
        int p = NBC + (idx - (NBC + NWC));
        float4 pad = make_float4(1e19f, 1e19f, 1e19f, 1e19f);
        bci[2*p] = pad;
        bci[2*p+1] = pad;
    } else if (idx < NBC + NWC + 512) {
        int p = NWC + (idx - (NBC + NWC + 256));
        float4 pad = make_float4(1e19f, 1e19f, 1e19f, 1e19f);
        wci[2*p] = pad;
        wci[2*p+1] = pad;
    }
}

// full sum over contributing sigmas (sigma >= 1) for the table build
__device__ __forceinline__ float sig13(float d, const Coef& co) {
    float s = 0.f;
    #pragma unroll
    for (int k = 6; k < 19; ++k) s += EXP2(d * co.c[k]);
    return s;
}

__device__ __forceinline__ float sqd(float4 a, float4 b) {
    float d0 = a.x - b.x, d1 = a.y - b.y, d2 = a.z - b.z, d3 = a.w - b.w;
    float d = d0 * d0;
    d = fmaf(d1, d1, d);
    d = fmaf(d2, d2, d);
    return fmaf(d3, d3, d);
}

// --- kernel 2b: build the global PL table (dead E_t region) -----------------
// midpoint-corrected chord per cell; cells never cross an exponent boundary.
__global__ __launch_bounds__(256) void build_tab(float* __restrict__ ws, Coef co) {
    int k = blockIdx.x * 256 + threadIdx.x;
    if (k >= TAB_N) return;
    unsigned u_lo = (unsigned)(TAB_BASE + k) << 16;
    float d_lo = __uint_as_float(u_lo);
    float d_mi = __uint_as_float(u_lo + 0x8000u);
    float d_hi = __uint_as_float(u_lo + 0x10000u);
    float f_lo = sig13(d_lo, co), f_mi = sig13(d_mi, co), f_hi = sig13(d_hi, co);
    float2 e;
    e.x = f_lo + 0.5f * (f_mi - 0.5f * (f_lo + f_hi));
    e.y = (f_hi - f_lo) * (1.0f / 65536.0f);
    ((float2*)(ws + WS_TAB))[k] = e;
}

// --- kernel 3: deep-queue table-only sweep ----------------------------------
// 12281 independent single-class blocks (~6.9 residency rounds at 7/CU) —
// the HW dispatcher backfills, so uneven placement self-heals. Per eval:
// sqd + one LDS PL lookup. NO queues, NO inline exps, NO flushes.
__global__ __launch_bounds__(256) void gk_tab(float* __restrict__ ws) {
    const float4* bci = (const float4*)(ws + WS_BCI);
    const float4* wci = (const float4*)(ws + WS_WCI);
    double* accs = (double*)((char*)ws + WS_ACC_BYTES);

    __shared__ float2 tabs[TAB_N];
    __shared__ float wsum[4][3];

    int tid = threadIdx.x;
    int lane = tid & 63, w = tid >> 6;

    {   // copy PL table global -> LDS (~5.5 float4 per thread)
        const float4* tg = (const float4*)(ws + WS_TAB);
        float4* td = (float4*)tabs;
        for (int k = tid; k < TAB_N / 2; k += 256) td[k] = tg[k];
    }
    __syncthreads();

    auto tab_get = [&](float d) -> float {
        unsigned u = __float_as_uint(d);
        int t = (int)(u >> 16) - TAB_BASE;
        t = min(max(t, 0), TAB_N - 1);
        float2 e = tabs[t];
        return fmaf((float)(u & 0xFFFFu), e.y, e.x);
    };

    float m0 = 0.f, m1 = 0.f, m2 = 0.f;   // per-thread partials, 3 jobs

    auto process = [&](const float4* __restrict__ Yv, int N, int i,
                       int par, int S) {
        int T = (N - i - 1 + 255) >> 8;
        int trips = (T - par + S - 1) / S;
        if (trips <= 0) return;
        float4 xs = Yv[2*i], xt = Yv[2*i+1];
        const float4* Yp = Yv + 2*((i + 1) + par*256 + tid);
        int stride = 512 * S;
        for (int t = 0; t < trips; ++t) {
            float4 ys = Yp[0], yt = Yp[1];
            Yp += stride;
            float dss = sqd(xs, ys), dtt = sqd(xt, yt);
            float dst = sqd(xs, yt), dts = sqd(xt, ys);
            m0 += tab_get(dss);
            m1 += tab_get(dtt);
            m2 += tab_get(dst) + tab_get(dts);
        }
    };

    int b = blockIdx.x;
    int jb;  // job base: wc jobs 0..2, bc jobs 3..5
    if (b < IT_BC_END) {                   // bc quarter-pair
        int p = b >> 2, oc = b & 3;
        jb = 3;
        process(bci, NBC, p,        oc, 4);
        process(bci, NBC, 6087 - p, oc, 4);
    } else if (b < IT_WC_END) {            // wc pair
        int i = b - IT_BC_END;
        jb = 0;
        process(wci, NWC, i,       0, 1);
        process(wci, NWC, 159 - i, 0, 1);
    } else {                               // st-diag strips
        int s = b - IT_WC_END;
        if (s < 24) {
            jb = 3;                        // -> job 5 (= jb + 2)
            int i0 = s * 256 + tid;
            if (i0 < NBC) m2 += tab_get(sqd(bci[2*i0], bci[2*i0+1]));
        } else {
            jb = 0;                        // -> job 2
            if (tid < NWC) m2 += tab_get(sqd(wci[2*tid], wci[2*tid+1]));
        }
    }

    // wave reduce (f32), cross-wave reduce, 3 atomics per block
    #pragma unroll
    for (int off = 32; off; off >>= 1) {
        m0 += __shfl_down(m0, off, 64);
        m1 += __shfl_down(m1, off, 64);
        m2 += __shfl_down(m2, off, 64);
    }
    if (lane == 0) { wsum[w][0] = m0; wsum[w][1] = m1; wsum[w][2] = m2; }
    __syncthreads();
    if (tid < 3) {
        double tot = (double)wsum[0][tid] + (double)wsum[1][tid]
                   + (double)wsum[2][tid] + (double)wsum[3][tid];
        if (tot != 0.0)
            atomicAdd(&accs[(jb + tid) * NSLOT + (b & (NSLOT - 1))], tot);
    }
}

// --- kernel 4: combine into the two output scalars --------------------------
__global__ void finalize(const float* __restrict__ ws, float* __restrict__ out) {
    const double* accs = (const double*)((const char*)ws + WS_ACC_BYTES);
    int lane = threadIdx.x;  // blockDim = 64
    double p[6];
    #pragma unroll
    for (int q = 0; q < 6; ++q) {
        p[q] = accs[q * NSLOT + lane];
        #pragma unroll
        for (int off = 32; off; off >>= 1) p[q] += __shfl_down(p[q], off, 64);
    }
    if (lane == 0) {
        double t0 = 2.0 * p[0] + 19.0 * NWC;   // self: 2*triangle + diag
        double t1 = 2.0 * p[1] + 19.0 * NWC;
        double t3 = 2.0 * p[3] + 19.0 * NBC;
        double t4 = 2.0 * p[4] + 19.0 * NBC;
        double nw = (double)NWC * (double)NWC;
        double nb = (double)NBC * (double)NBC;
        out[0] = (float)((t0 + t1 - 2.0 * p[2]) / nw);   // p2 = full st sum
        out[1] = (float)((t3 + t4 - 2.0 * p[5]) / nb);
    }
}

extern "C" void kernel_launch(void* const* d_in, const int* in_sizes, int n_in,
                              void* d_out, int out_size, void* d_ws, size_t ws_size,
                              hipStream_t stream) {
    const float* src = (const float*)d_in[0];
    const float* tgt = (const float*)d_in[1];
    float* out = (float*)d_out;
    float* ws = (float*)d_ws;

    static const double SIG[19] = {1e-06, 1e-05, 1e-04, 1e-03, 1e-02, 1e-01,
                                   1.0, 5.0, 10.0, 15.0, 20.0, 25.0, 30.0,
                                   35.0, 100.0, 1e3, 1e4, 1e5, 1e6};
    Coef co;
    for (int k = 0; k < 19; ++k)
        co.c[k] = (float)(-1.0 / (2.0 * SIG[k] * 0.6931471805599453));  // -log2e/(2s)

    compute_E<<<200, 256, 0, stream>>>(src, tgt, ws);
    scatter<<<27, 256, 0, stream>>>(ws);
    build_tab<<<11, 256, 0, stream>>>(ws, co);
    gk_tab<<<GK_GRID, 256, 0, stream>>>(ws);
    finalize<<<1, 64, 0, stream>>>(ws, out);
}

// Round 14
// 63.888 us; speedup vs baseline: 5.1283x; 1.0735x over previous
//
#include <hip/hip_runtime.h>

// ---------------------------------------------------------------------------
// MaximumMeanDiscrepancy: BATCH=160, INSTANCES=4, FEAT=1024, P=40
// out[0] = mmd(wcs, wct), out[1] = mmd(bcs, bct)
// ---------------------------------------------------------------------------

#define FEAT   1024
#define NROW   160     // BATCH
#define NBC    6088    // (1 + 39*39) * 4
#define NWC    160
#define NPAD   768     // pad rows (512-wide trip overrun safety)

// workspace layout (float offsets). bci/wci INTERLEAVED: row i = {src f4, tgt f4}.
// NPAD pad rows of 1e19f follow each array (pad d -> clamps to top table cell
// ~5e-8 -> bias < 1e-8 on outputs). Global PL table (float2[2816]) lives in
// the dead E_t region (E dead after scatter; build_tab runs after).
#define WS_ES   0          // E_s [160*160]
#define WS_ET   25600      // E_t [160*160]  (later: PL table float2[2816])
#define WS_TAB  25600
#define WS_BCI  51200      // bci [(6088+768)*8] -> ends 106048
#define WS_WCI  106048     // wci [(160+768)*8] -> ends 113472
#define WS_ACC_BYTES 453888  // 6*64 doubles
#define NSLOT  64

// Full-range PL table: S(d) = sum over sigma in {1,5,10,15,20,25,30,35,100,
// 1e3,1e4,1e5,1e6} of exp2(d*c_sigma), d in [8, 2^25), 128 cells/octave,
// bits-indexed by (float_bits>>16) - 16640. sigma <= 0.1 is < 4e-18 for d>=8
// (vanishes exactly in f32 addition). d < 8 clamps to cell 0 (P ~ 1e-8);
// d >= 2^25 clamps to the top cell (~5e-8). Midpoint-corrected chord per
// cell: |err| <= ~3e-6 per eval in the multi-sigma curvature zone.
#define TAB_N    2816
#define TAB_BASE 16640     // bits(8.0f) >> 16

// deep-queue grid of 512-thread blocks:
//   [0, 6088)     bc half-pairs: p = b>>1 rows {p,6087-p}, phase b&1, S=2
//   [6088, 6168)  wc pairs {i, 159-i}
//   [6168, 6181)  st-diag strips (12 bc x 512 + 1 wc)
#define IT_BC_END 6088
#define IT_WC_END 6168
#define GK_GRID   6181

struct Coef { float c[19]; };  // c[k] = -log2(e)/(2*sigma_k)  (exp2 form)

#if defined(__has_builtin)
#if __has_builtin(__builtin_amdgcn_exp2f)
#define EXP2(x) __builtin_amdgcn_exp2f(x)
#else
#define EXP2(x) exp2f(x)
#endif
#else
#define EXP2(x) exp2f(x)
#endif

// --- kernel 1: E[a,b] = ||f_a - f_b||^2 for both sides, 16x16 tiles ---------
__global__ __launch_bounds__(256) void compute_E(const float* __restrict__ Fs,
                                                 const float* __restrict__ Ft,
                                                 float* __restrict__ ws) {
    int side = blockIdx.x / 100;          // 0 = source, 1 = target
    int tile = blockIdx.x % 100;
    int trow = tile / 10, tcol = tile % 10;
    const float* F = side ? Ft : Fs;
    float* E = ws + (side ? WS_ET : WS_ES);

    __shared__ float As[16][132];
    __shared__ float Bs[16][132];
    int tid = threadIdx.x;
    int ti = tid >> 4, tj = tid & 15;
    int lr = tid >> 5;        // 0..7
    int lc4 = tid & 31;       // float4 column (0..31) of 128-dim chunk

    float acc = 0.f;
    for (int ch = 0; ch < 8; ++ch) {
        for (int rr = lr; rr < 16; rr += 8) {
            float4 a = *(const float4*)(F + (trow*16+rr)*FEAT + ch*128 + lc4*4);
            *(float4*)(&As[rr][lc4*4]) = a;
            float4 b = *(const float4*)(F + (tcol*16+rr)*FEAT + ch*128 + lc4*4);
            *(float4*)(&Bs[rr][lc4*4]) = b;
        }
        __syncthreads();
        #pragma unroll
        for (int c = 0; c < 128; c += 4) {
            float4 a = *(const float4*)(&As[ti][c]);
            float4 b = *(const float4*)(&Bs[tj][c]);
            float d0 = a.x - b.x, d1 = a.y - b.y, d2 = a.z - b.z, d3 = a.w - b.w;
            acc = fmaf(d0, d0, acc);
            acc = fmaf(d1, d1, acc);
            acc = fmaf(d2, d2, acc);
            acc = fmaf(d3, d3, acc);
        }
        __syncthreads();
    }
    E[(trow*16+ti)*NROW + tcol*16 + tj] = acc;
}

// --- kernel 2: gather interleaved bci/wci rows; pad; zero accumulators ------
__global__ __launch_bounds__(256) void scatter(float* __restrict__ ws) {
    int idx = blockIdx.x * blockDim.x + threadIdx.x;
    const float* E_s = ws + WS_ES;
    const float* E_t = ws + WS_ET;
    float4* bci = (float4*)(ws + WS_BCI);
    float4* wci = (float4*)(ws + WS_WCI);
    double* accs = (double*)((char*)ws + WS_ACC_BYTES);

    if (idx < 6 * NSLOT) accs[idx] = 0.0;

    if (idx < NBC) {
        int t = idx >> 2, ii = idx & 3;
        int pi, pj;
        if (t == 0) { pi = 0; pj = 1; }
        else {
            int tt = t - 1;
            pi = 1 + tt / 39;
            int jj = tt % 39;
            pj = (jj < pi) ? jj : jj + 1;
        }
        bci[2*idx]   = *(const float4*)(E_s + (4*pi + ii)*NROW + 4*pj);
        bci[2*idx+1] = *(const float4*)(E_t + (4*pi + ii)*NROW + 4*pj);
    } else if (idx < NBC + NWC) {
        int r = idx - NBC;
        int p = r >> 2;
        wci[2*r]   = *(const float4*)(E_s + r*NROW + 4*p);
        wci[2*r+1] = *(const float4*)(E_t + r*NROW + 4*p);
    } else if (idx < NBC + NWC + NPAD) {
        int p = NBC + (idx - (NBC + NWC));
        float4 pad = make_float4(1e19f, 1e19f, 1e19f, 1e19f);
        bci[2*p] = pad;
        bci[2*p+1] = pad;
    } else if (idx < NBC + NWC + 2*NPAD) {
        int p = NWC + (idx - (NBC + NWC + NPAD));
        float4 pad = make_float4(1e19f, 1e19f, 1e19f, 1e19f);
        wci[2*p] = pad;
        wci[2*p+1] = pad;
    }
}

// full sum over contributing sigmas (sigma >= 1) for the table build
__device__ __forceinline__ float sig13(float d, const Coef& co) {
    float s = 0.f;
    #pragma unroll
    for (int k = 6; k < 19; ++k) s += EXP2(d * co.c[k]);
    return s;
}

__device__ __forceinline__ float sqd(float4 a, float4 b) {
    float d0 = a.x - b.x, d1 = a.y - b.y, d2 = a.z - b.z, d3 = a.w - b.w;
    float d = d0 * d0;
    d = fmaf(d1, d1, d);
    d = fmaf(d2, d2, d);
    return fmaf(d3, d3, d);
}

// --- kernel 2b: build the global PL table (dead E_t region) -----------------
// midpoint-corrected chord per cell; cells never cross an exponent boundary.
__global__ __launch_bounds__(256) void build_tab(float* __restrict__ ws, Coef co) {
    int k = blockIdx.x * 256 + threadIdx.x;
    if (k >= TAB_N) return;
    unsigned u_lo = (unsigned)(TAB_BASE + k) << 16;
    float d_lo = __uint_as_float(u_lo);
    float d_mi = __uint_as_float(u_lo + 0x8000u);
    float d_hi = __uint_as_float(u_lo + 0x10000u);
    float f_lo = sig13(d_lo, co), f_mi = sig13(d_mi, co), f_hi = sig13(d_hi, co);
    float2 e;
    e.x = f_lo + 0.5f * (f_mi - 0.5f * (f_lo + f_hi));
    e.y = (f_hi - f_lo) * (1.0f / 65536.0f);
    ((float2*)(ws + WS_TAB))[k] = e;
}

// --- kernel 3: deep-queue table-only sweep, 512-thread blocks ---------------
// 6181 independent blocks (8 waves each, 4 blocks/CU -> 32/32 wave cap,
// ~6 residency rounds). Per eval: sqd + one LDS PL lookup. NO queues, NO
// inline exps. Table copy amortized over ~6 x 512-wide trips.
__global__ __launch_bounds__(512) void gk_tab(float* __restrict__ ws) {
    const float4* bci = (const float4*)(ws + WS_BCI);
    const float4* wci = (const float4*)(ws + WS_WCI);
    double* accs = (double*)((char*)ws + WS_ACC_BYTES);

    __shared__ float2 tabs[TAB_N];
    __shared__ float wsum[8][3];

    int tid = threadIdx.x;
    int lane = tid & 63, w = tid >> 6;

    {   // copy PL table global -> LDS (~2.75 float4 per thread)
        const float4* tg = (const float4*)(ws + WS_TAB);
        float4* td = (float4*)tabs;
        for (int k = tid; k < TAB_N / 2; k += 512) td[k] = tg[k];
    }
    __syncthreads();

    auto tab_get = [&](float d) -> float {
        unsigned u = __float_as_uint(d);
        int t = (int)(u >> 16) - TAB_BASE;
        t = min(max(t, 0), TAB_N - 1);
        float2 e = tabs[t];
        return fmaf((float)(u & 0xFFFFu), e.y, e.x);
    };

    float m0 = 0.f, m1 = 0.f, m2 = 0.f;   // per-thread partials, 3 jobs

    auto process = [&](const float4* __restrict__ Yv, int N, int i,
                       int par, int S) {
        int T = (N - i - 1 + 511) >> 9;
        int trips = (T - par + S - 1) / S;
        if (trips <= 0) return;
        float4 xs = Yv[2*i], xt = Yv[2*i+1];
        const float4* Yp = Yv + 2*((i + 1) + par*512 + tid);
        int stride = 1024 * S;
        for (int t = 0; t < trips; ++t) {
            float4 ys = Yp[0], yt = Yp[1];
            Yp += stride;
            float dss = sqd(xs, ys), dtt = sqd(xt, yt);
            float dst = sqd(xs, yt), dts = sqd(xt, ys);
            m0 += tab_get(dss);
            m1 += tab_get(dtt);
            m2 += tab_get(dst) + tab_get(dts);
        }
    };

    int b = blockIdx.x;
    int jb;  // job base: wc jobs 0..2, bc jobs 3..5
    if (b < IT_BC_END) {                   // bc half-pair
        int p = b >> 1, h = b & 1;
        jb = 3;
        process(bci, NBC, p,        h, 2);
        process(bci, NBC, 6087 - p, h, 2);
    } else if (b < IT_WC_END) {            // wc pair
        int i = b - IT_BC_END;
        jb = 0;
        process(wci, NWC, i,       0, 1);
        process(wci, NWC, 159 - i, 0, 1);
    } else {                               // st-diag strips
        int s = b - IT_WC_END;
        if (s < 12) {
            jb = 3;                        // -> job 5 (= jb + 2)
            int i0 = s * 512 + tid;
            if (i0 < NBC) m2 += tab_get(sqd(bci[2*i0], bci[2*i0+1]));
        } else {
            jb = 0;                        // -> job 2
            if (tid < NWC) m2 += tab_get(sqd(wci[2*tid], wci[2*tid+1]));
        }
    }

    // wave reduce (f32), cross-wave reduce, 3 atomics per block
    #pragma unroll
    for (int off = 32; off; off >>= 1) {
        m0 += __shfl_down(m0, off, 64);
        m1 += __shfl_down(m1, off, 64);
        m2 += __shfl_down(m2, off, 64);
    }
    if (lane == 0) { wsum[w][0] = m0; wsum[w][1] = m1; wsum[w][2] = m2; }
    __syncthreads();
    if (tid < 3) {
        double tot = 0.0;
        #pragma unroll
        for (int q = 0; q < 8; ++q) tot += (double)wsum[q][tid];
        if (tot != 0.0)
            atomicAdd(&accs[(jb + tid) * NSLOT + (b & (NSLOT - 1))], tot);
    }
}

// --- kernel 4: combine into the two output scalars --------------------------
__global__ void finalize(const float* __restrict__ ws, float* __restrict__ out) {
    const double* accs = (const double*)((const char*)ws + WS_ACC_BYTES);
    int lane = threadIdx.x;  // blockDim = 64
    double p[6];
    #pragma unroll
    for (int q = 0; q < 6; ++q) {
        p[q] = accs[q * NSLOT + lane];
        #pragma unroll
        for (int off = 32; off; off >>= 1) p[q] += __shfl_down(p[q], off, 64);
    }
    if (lane == 0) {
        double t0 = 2.0 * p[0] + 19.0 * NWC;   // self: 2*triangle + diag
        double t1 = 2.0 * p[1] + 19.0 * NWC;
        double t3 = 2.0 * p[3] + 19.0 * NBC;
        double t4 = 2.0 * p[4] + 19.0 * NBC;
        double nw = (double)NWC * (double)NWC;
        double nb = (double)NBC * (double)NBC;
        out[0] = (float)((t0 + t1 - 2.0 * p[2]) / nw);   // p2 = full st sum
        out[1] = (float)((t3 + t4 - 2.0 * p[5]) / nb);
    }
}

extern "C" void kernel_launch(void* const* d_in, const int* in_sizes, int n_in,
                              void* d_out, int out_size, void* d_ws, size_t ws_size,
                              hipStream_t stream) {
    const float* src = (const float*)d_in[0];
    const float* tgt = (const float*)d_in[1];
    float* out = (float*)d_out;
    float* ws = (float*)d_ws;

    static const double SIG[19] = {1e-06, 1e-05, 1e-04, 1e-03, 1e-02, 1e-01,
                                   1.0, 5.0, 10.0, 15.0, 20.0, 25.0, 30.0,
                                   35.0, 100.0, 1e3, 1e4, 1e5, 1e6};
    Coef co;
    for (int k = 0; k < 19; ++k)
        co.c[k] = (float)(-1.0 / (2.0 * SIG[k] * 0.6931471805599453));  // -log2e/(2s)

    compute_E<<<200, 256, 0, stream>>>(src, tgt, ws);
    scatter<<<31, 256, 0, stream>>>(ws);
    build_tab<<<11, 256, 0, stream>>>(ws, co);
    gk_tab<<<GK_GRID, 512, 0, stream>>>(ws);
    finalize<<<1, 64, 0, stream>>>(ws, out);
}

// Round 15
// 57.440 us; speedup vs baseline: 5.7040x; 1.1123x over previous
//
#include <hip/hip_runtime.h>

// ---------------------------------------------------------------------------
// MaximumMeanDiscrepancy: BATCH=160, INSTANCES=4, FEAT=1024, P=40
// out[0] = mmd(wcs, wct), out[1] = mmd(bcs, bct)
// ---------------------------------------------------------------------------

#define FEAT   1024
#define NROW   160     // BATCH
#define NBC    6088    // (1 + 39*39) * 4
#define NWC    160
#define NPAD   512     // pad rows (512-wide trip overrun <= 511)

// workspace layout (float offsets). bci/wci INTERLEAVED: row i = {src f4, tgt f4}.
// NPAD pad rows of 1e19f follow each array; pad d overflows to +inf -> top
// table cell, and the combo (ss+tt-st-ts) of identical values cancels EXACTLY.
// The PL table has its own region (no overlap), so build_tab merges into the
// compute_E launch.
#define WS_ES   0          // E_s [160*160]
#define WS_ET   25600      // E_t [160*160]
#define WS_BCI  51200      // bci [(6088+512)*8] -> ends 104000
#define WS_WCI  104000     // wci [(160+512)*8] -> ends 109376
#define WS_TAB  109376     // PL table float2[2816] -> ends 115008
#define WS_ACC_BYTES 460032  // 4*64 doubles
#define NSLOT  64

// Full-range PL table: S(d) = sum over sigma in {1,5,10,15,20,25,30,35,100,
// 1e3,1e4,1e5,1e6} of exp2(d*c_sigma), d in [8, 2^25), 128 cells/octave,
// bits-indexed by (float_bits>>16) - 16640. sigma <= 0.1 is < 4e-18 for d>=8
// (vanishes exactly in f32 addition). d < 8 clamps to cell 0 (P ~ 1e-8).
// Midpoint-corrected chord per cell: |err| <= ~3e-6 per eval.
#define TAB_N    2816
#define TAB_BASE 16640     // bits(8.0f) >> 16

// gk grid (512-thread blocks):
//   [0, 6088)     bc duo quarter-sweeps: pp = b>>2 duos {2pp,2pp+1} and
//                 {6086-2pp, 6087-2pp}, phase h = b&3, S=4
//   [6088, 6128)  wc duos {2m, 2m+1} and {158-2m, 159-2m}, full sweep
//   [6128, 6141)  st-diag strips (12 bc x 512 + 1 wc)
#define GK_BC    6088
#define GK_WCEND 6128
#define GK_GRID  6141

struct Coef { float c[19]; };  // c[k] = -log2(e)/(2*sigma_k)  (exp2 form)

#if defined(__has_builtin)
#if __has_builtin(__builtin_amdgcn_exp2f)
#define EXP2(x) __builtin_amdgcn_exp2f(x)
#else
#define EXP2(x) exp2f(x)
#endif
#else
#define EXP2(x) exp2f(x)
#endif

// full sum over contributing sigmas (sigma >= 1) for the table build
__device__ __forceinline__ float sig13(float d, const Coef& co) {
    float s = 0.f;
    #pragma unroll
    for (int k = 6; k < 19; ++k) s += EXP2(d * co.c[k]);
    return s;
}

__device__ __forceinline__ float sqd(float4 a, float4 b) {
    float d0 = a.x - b.x, d1 = a.y - b.y, d2 = a.z - b.z, d3 = a.w - b.w;
    float d = d0 * d0;
    d = fmaf(d1, d1, d);
    d = fmaf(d2, d2, d);
    return fmaf(d3, d3, d);
}

// --- kernel 1: compute E (blocks 0..199) + build PL table (blocks 200..210) -
__global__ __launch_bounds__(256) void compute_E_tab(const float* __restrict__ Fs,
                                                     const float* __restrict__ Ft,
                                                     float* __restrict__ ws, Coef co) {
    int b = blockIdx.x;
    if (b >= 200) {            // ---- build table: 11 blocks x 256 = 2816 cells
        int k = (b - 200) * 256 + threadIdx.x;
        unsigned u_lo = (unsigned)(TAB_BASE + k) << 16;
        float d_lo = __uint_as_float(u_lo);
        float d_mi = __uint_as_float(u_lo + 0x8000u);
        float d_hi = __uint_as_float(u_lo + 0x10000u);
        float f_lo = sig13(d_lo, co), f_mi = sig13(d_mi, co), f_hi = sig13(d_hi, co);
        float2 e;
        e.x = f_lo + 0.5f * (f_mi - 0.5f * (f_lo + f_hi));
        e.y = (f_hi - f_lo) * (1.0f / 65536.0f);
        ((float2*)(ws + WS_TAB))[k] = e;
        return;
    }
    // ---- E[a,b] = ||f_a - f_b||^2, 16x16 tiles
    int side = b / 100;
    int tile = b % 100;
    int trow = tile / 10, tcol = tile % 10;
    const float* F = side ? Ft : Fs;
    float* E = ws + (side ? WS_ET : WS_ES);

    __shared__ float As[16][132];
    __shared__ float Bs[16][132];
    int tid = threadIdx.x;
    int ti = tid >> 4, tj = tid & 15;
    int lr = tid >> 5;        // 0..7
    int lc4 = tid & 31;       // float4 column of 128-dim chunk

    float acc = 0.f;
    for (int ch = 0; ch < 8; ++ch) {
        for (int rr = lr; rr < 16; rr += 8) {
            float4 a = *(const float4*)(F + (trow*16+rr)*FEAT + ch*128 + lc4*4);
            *(float4*)(&As[rr][lc4*4]) = a;
            float4 bb = *(const float4*)(F + (tcol*16+rr)*FEAT + ch*128 + lc4*4);
            *(float4*)(&Bs[rr][lc4*4]) = bb;
        }
        __syncthreads();
        #pragma unroll
        for (int c = 0; c < 128; c += 4) {
            float4 a = *(const float4*)(&As[ti][c]);
            float4 bb = *(const float4*)(&Bs[tj][c]);
            float d0 = a.x - bb.x, d1 = a.y - bb.y, d2 = a.z - bb.z, d3 = a.w - bb.w;
            acc = fmaf(d0, d0, acc);
            acc = fmaf(d1, d1, acc);
            acc = fmaf(d2, d2, acc);
            acc = fmaf(d3, d3, acc);
        }
        __syncthreads();
    }
    E[(trow*16+ti)*NROW + tcol*16 + tj] = acc;
}

// --- kernel 2: gather interleaved bci/wci rows; pad; zero accumulators ------
__global__ __launch_bounds__(256) void scatter(float* __restrict__ ws) {
    int idx = blockIdx.x * blockDim.x + threadIdx.x;
    const float* E_s = ws + WS_ES;
    const float* E_t = ws + WS_ET;
    float4* bci = (float4*)(ws + WS_BCI);
    float4* wci = (float4*)(ws + WS_WCI);
    double* accs = (double*)((char*)ws + WS_ACC_BYTES);

    if (idx < 4 * NSLOT) accs[idx] = 0.0;

    if (idx < NBC) {
        int t = idx >> 2, ii = idx & 3;
        int pi, pj;
        if (t == 0) { pi = 0; pj = 1; }
        else {
            int tt = t - 1;
            pi = 1 + tt / 39;
            int jj = tt % 39;
            pj = (jj < pi) ? jj : jj + 1;
        }
        bci[2*idx]   = *(const float4*)(E_s + (4*pi + ii)*NROW + 4*pj);
        bci[2*idx+1] = *(const float4*)(E_t + (4*pi + ii)*NROW + 4*pj);
    } else if (idx < NBC + NWC) {
        int r = idx - NBC;
        int p = r >> 2;
        wci[2*r]   = *(const float4*)(E_s + r*NROW + 4*p);
        wci[2*r+1] = *(const float4*)(E_t + r*NROW + 4*p);
    } else if (idx < NBC + NWC + NPAD) {
        int p = NBC + (idx - (NBC + NWC));
        float4 pad = make_float4(1e19f, 1e19f, 1e19f, 1e19f);
        bci[2*p] = pad;
        bci[2*p+1] = pad;
    } else if (idx < NBC + NWC + 2*NPAD) {
        int p = NWC + (idx - (NBC + NWC + NPAD));
        float4 pad = make_float4(1e19f, 1e19f, 1e19f, 1e19f);
        wci[2*p] = pad;
        wci[2*p+1] = pad;
    }
}

// --- kernel 3: duo-fused table sweep ----------------------------------------
// Per trip: ONE y-pair load (2 f4) -> 8 evals (2 duo rows x 4 combos), one
// combo accumulator: C = (k_ss + k_tt) - (k_st + k_ts). Duo-internal pair
// added analytically by lane 0 of the h==0 block. Pad quads cancel exactly.
__global__ __launch_bounds__(512, 8) void gk_duo(float* __restrict__ ws) {
    const float4* bci = (const float4*)(ws + WS_BCI);
    const float4* wci = (const float4*)(ws + WS_WCI);
    double* accs = (double*)((char*)ws + WS_ACC_BYTES);

    __shared__ float2 tabs[TAB_N];
    __shared__ float wsum[8][2];

    int tid = threadIdx.x;
    int lane = tid & 63, w = tid >> 6;

    {   // copy PL table global -> LDS (~2.75 float4 per thread)
        const float4* tg = (const float4*)(ws + WS_TAB);
        float4* td = (float4*)tabs;
        for (int k = tid; k < TAB_N / 2; k += 512) td[k] = tg[k];
    }
    __syncthreads();

    auto tab_get = [&](float d) -> float {
        unsigned u = __float_as_uint(d);
        int t = (int)(u >> 16) - TAB_BASE;
        t = min(max(t, 0), TAB_N - 1);
        float2 e = tabs[t];
        return fmaf((float)(u & 0xFFFFu), e.y, e.x);
    };

    float mc = 0.f, md = 0.f;   // combo, st-diag partials

    // duo (a, a+1) vs shared j in [a+2, N), phase h of S
    auto duo_sweep = [&](const float4* __restrict__ Yv, int N, int a,
                         int h, int S) {
        float4 xs0 = Yv[2*a],   xt0 = Yv[2*a+1];
        float4 xs1 = Yv[2*a+2], xt1 = Yv[2*a+3];
        if (h == 0 && tid == 0) {    // duo-internal pair (a, a+1)
            mc += (tab_get(sqd(xs0, xs1)) + tab_get(sqd(xt0, xt1)))
                - (tab_get(sqd(xs0, xt1)) + tab_get(sqd(xt0, xs1)));
        }
        int jbeg = a + 2;
        int T = (N - jbeg + 511) >> 9;
        int trips = (T - h + S - 1) / S;
        if (trips <= 0) return;
        const float4* Yp = Yv + 2*(jbeg + h*512 + tid);
        int stride = 1024 * S;
        for (int t = 0; t < trips; ++t) {
            float4 ys = Yp[0], yt = Yp[1];
            Yp += stride;
            float a0 = tab_get(sqd(xs0, ys)), a1 = tab_get(sqd(xt0, yt));
            float a2 = tab_get(sqd(xs0, yt)), a3 = tab_get(sqd(xt0, ys));
            float a4 = tab_get(sqd(xs1, ys)), a5 = tab_get(sqd(xt1, yt));
            float a6 = tab_get(sqd(xs1, yt)), a7 = tab_get(sqd(xt1, ys));
            mc += ((a0 + a1) - (a2 + a3)) + ((a4 + a5) - (a6 + a7));
        }
    };

    int b = blockIdx.x;
    int cls;   // 0 = wc (slots 0,1), 1 = bc (slots 2,3)
    if (b < GK_BC) {                       // bc duo quarter-sweep
        int pp = b >> 2, h = b & 3;
        cls = 1;
        duo_sweep(bci, NBC, 2*pp,        h, 4);
        duo_sweep(bci, NBC, 6086 - 2*pp, h, 4);
    } else if (b < GK_WCEND) {             // wc duo full sweep
        int m = b - GK_BC;
        cls = 0;
        duo_sweep(wci, NWC, 2*m,       0, 1);
        duo_sweep(wci, NWC, 158 - 2*m, 0, 1);
    } else {                               // st-diag strips
        int s = b - GK_WCEND;
        if (s < 12) {
            cls = 1;
            int i0 = s * 512 + tid;
            if (i0 < NBC) md += tab_get(sqd(bci[2*i0], bci[2*i0+1]));
        } else {
            cls = 0;
            if (tid < NWC) md += tab_get(sqd(wci[2*tid], wci[2*tid+1]));
        }
    }

    // wave reduce (f32), cross-wave reduce, 2 atomics per block
    #pragma unroll
    for (int off = 32; off; off >>= 1) {
        mc += __shfl_down(mc, off, 64);
        md += __shfl_down(md, off, 64);
    }
    if (lane == 0) { wsum[w][0] = mc; wsum[w][1] = md; }
    __syncthreads();
    if (tid < 2) {
        double tot = 0.0;
        #pragma unroll
        for (int q = 0; q < 8; ++q) tot += (double)wsum[q][tid];
        if (tot != 0.0)
            atomicAdd(&accs[(cls * 2 + tid) * NSLOT + (b & (NSLOT - 1))], tot);
    }
}

// --- kernel 4: combine into the two output scalars --------------------------
// numerator = 2*combo + 38*N - 2*diag;  out = numerator / N^2
__global__ void finalize(const float* __restrict__ ws, float* __restrict__ out) {
    const double* accs = (const double*)((const char*)ws + WS_ACC_BYTES);
    int lane = threadIdx.x;  // blockDim = 64
    double p[4];
    #pragma unroll
    for (int q = 0; q < 4; ++q) {
        p[q] = accs[q * NSLOT + lane];
        #pragma unroll
        for (int off = 32; off; off >>= 1) p[q] += __shfl_down(p[q], off, 64);
    }
    if (lane == 0) {
        double nw = (double)NWC * (double)NWC;
        double nb = (double)NBC * (double)NBC;
        out[0] = (float)((2.0 * p[0] + 38.0 * NWC - 2.0 * p[1]) / nw);
        out[1] = (float)((2.0 * p[2] + 38.0 * NBC - 2.0 * p[3]) / nb);
    }
}

extern "C" void kernel_launch(void* const* d_in, const int* in_sizes, int n_in,
                              void* d_out, int out_size, void* d_ws, size_t ws_size,
                              hipStream_t stream) {
    const float* src = (const float*)d_in[0];
    const float* tgt = (const float*)d_in[1];
    float* out = (float*)d_out;
    float* ws = (float*)d_ws;

    static const double SIG[19] = {1e-06, 1e-05, 1e-04, 1e-03, 1e-02, 1e-01,
                                   1.0, 5.0, 10.0, 15.0, 20.0, 25.0, 30.0,
                                   35.0, 100.0, 1e3, 1e4, 1e5, 1e6};
    Coef co;
    for (int k = 0; k < 19; ++k)
        co.c[k] = (float)(-1.0 / (2.0 * SIG[k] * 0.6931471805599453));  // -log2e/(2s)

    compute_E_tab<<<211, 256, 0, stream>>>(src, tgt, ws, co);
    scatter<<<29, 256, 0, stream>>>(ws);
    gk_duo<<<GK_GRID, 512, 0, stream>>>(ws);
    finalize<<<1, 64, 0, stream>>>(ws, out);
}

// Round 16
// 49.326 us; speedup vs baseline: 6.6423x; 1.1645x over previous
//
#include <hip/hip_runtime.h>

// ---------------------------------------------------------------------------
// MaximumMeanDiscrepancy: BATCH=160, INSTANCES=4, FEAT=1024, P=40
// out[0] = mmd(wcs, wct), out[1] = mmd(bcs, bct)
// ---------------------------------------------------------------------------

#define FEAT   1024
#define NROW   160     // BATCH
#define NBC    6088    // (1 + 39*39) * 4
#define NWC    160
#define NPAD   512     // pad rows (512-wide trip overrun <= 511)

// workspace layout (float offsets). bci/wci INTERLEAVED: row i = {src f4, tgt f4}.
// NPAD pad rows of 1e19f follow each array; pad rows have identical s/t parts
// so the combo (ss+tt-st-ts) cancels EXACTLY for any x.
#define WS_ES   0          // E_s [160*160]
#define WS_ET   25600      // E_t [160*160]
#define WS_BCI  51200      // bci [(6088+512)*8] -> ends 104000
#define WS_WCI  104000     // wci [(160+512)*8] -> ends 109376
#define WS_TAB  109376     // PL table float2[2816] -> ends 115008
#define WS_ACC_BYTES 460032  // 4*64 doubles
#define NSLOT  64

// Full-range PL table: S(d) = sum over sigma in {1,5,10,15,20,25,30,35,100,
// 1e3,1e4,1e5,1e6} of exp2(d*c_sigma), d in [8, 2^25), 128 cells/octave,
// bits-indexed by (float_bits>>16) - 16640. sigma <= 0.1 is < 4e-18 for d>=8
// (vanishes exactly in f32 addition). d < 8 clamps to cell 0 (P ~ 1e-8).
// Midpoint-corrected chord per cell: |err| <= ~3e-6 per eval.
#define TAB_N    2816
#define TAB_BASE 16640     // bits(8.0f) >> 16

// gk grid (512-thread blocks):
//   [0, 1522)       bc quad sweeps: pp = b>>1 -> quads pp and 1521-pp
//                   (rows 4q..4q+3 vs j >= 4q+4), phase h = b&1, S=2.
//                   Equal length: the two quads' sweeps sum to ~6084 rows.
//   [1522, 1542)    wc quad sweeps: m -> quads m and 39-m, full (S=1)
//   [1542, 1554)    bc st-diag strips (12 x 512)
//   [1554, 1555)    wc st-diag strip
//   [1555, 1573)    bc quad-internal pairs (1522*6 = 9132, 18 x 512)
//   [1573, 1574)    wc quad-internal pairs (240, 1 block)
#define GK_BCS  1522
#define GK_WCS  1542
#define GK_BD   1554
#define GK_WD   1555
#define GK_BI   1573
#define GK_GRID 1574

struct Coef { float c[19]; };  // c[k] = -log2(e)/(2*sigma_k)  (exp2 form)

#if defined(__has_builtin)
#if __has_builtin(__builtin_amdgcn_exp2f)
#define EXP2(x) __builtin_amdgcn_exp2f(x)
#else
#define EXP2(x) exp2f(x)
#endif
#else
#define EXP2(x) exp2f(x)
#endif

// full sum over contributing sigmas (sigma >= 1) for the table build
__device__ __forceinline__ float sig13(float d, const Coef& co) {
    float s = 0.f;
    #pragma unroll
    for (int k = 6; k < 19; ++k) s += EXP2(d * co.c[k]);
    return s;
}

__device__ __forceinline__ float sqd(float4 a, float4 b) {
    float d0 = a.x - b.x, d1 = a.y - b.y, d2 = a.z - b.z, d3 = a.w - b.w;
    float d = d0 * d0;
    d = fmaf(d1, d1, d);
    d = fmaf(d2, d2, d);
    return fmaf(d3, d3, d);
}

// --- kernel 1: compute E (blocks 0..199) + build PL table (blocks 200..210) -
__global__ __launch_bounds__(256) void compute_E_tab(const float* __restrict__ Fs,
                                                     const float* __restrict__ Ft,
                                                     float* __restrict__ ws, Coef co) {
    int b = blockIdx.x;
    if (b >= 200) {            // ---- build table: 11 blocks x 256 = 2816 cells
        int k = (b - 200) * 256 + threadIdx.x;
        unsigned u_lo = (unsigned)(TAB_BASE + k) << 16;
        float d_lo = __uint_as_float(u_lo);
        float d_mi = __uint_as_float(u_lo + 0x8000u);
        float d_hi = __uint_as_float(u_lo + 0x10000u);
        float f_lo = sig13(d_lo, co), f_mi = sig13(d_mi, co), f_hi = sig13(d_hi, co);
        float2 e;
        e.x = f_lo + 0.5f * (f_mi - 0.5f * (f_lo + f_hi));
        e.y = (f_hi - f_lo) * (1.0f / 65536.0f);
        ((float2*)(ws + WS_TAB))[k] = e;
        return;
    }
    // ---- E[a,b] = ||f_a - f_b||^2, 16x16 tiles
    int side = b / 100;
    int tile = b % 100;
    int trow = tile / 10, tcol = tile % 10;
    const float* F = side ? Ft : Fs;
    float* E = ws + (side ? WS_ET : WS_ES);

    __shared__ float As[16][132];
    __shared__ float Bs[16][132];
    int tid = threadIdx.x;
    int ti = tid >> 4, tj = tid & 15;
    int lr = tid >> 5;        // 0..7
    int lc4 = tid & 31;       // float4 column of 128-dim chunk

    float acc = 0.f;
    for (int ch = 0; ch < 8; ++ch) {
        for (int rr = lr; rr < 16; rr += 8) {
            float4 a = *(const float4*)(F + (trow*16+rr)*FEAT + ch*128 + lc4*4);
            *(float4*)(&As[rr][lc4*4]) = a;
            float4 bb = *(const float4*)(F + (tcol*16+rr)*FEAT + ch*128 + lc4*4);
            *(float4*)(&Bs[rr][lc4*4]) = bb;
        }
        __syncthreads();
        #pragma unroll
        for (int c = 0; c < 128; c += 4) {
            float4 a = *(const float4*)(&As[ti][c]);
            float4 bb = *(const float4*)(&Bs[tj][c]);
            float d0 = a.x - bb.x, d1 = a.y - bb.y, d2 = a.z - bb.z, d3 = a.w - bb.w;
            acc = fmaf(d0, d0, acc);
            acc = fmaf(d1, d1, acc);
            acc = fmaf(d2, d2, acc);
            acc = fmaf(d3, d3, acc);
        }
        __syncthreads();
    }
    E[(trow*16+ti)*NROW + tcol*16 + tj] = acc;
}

// --- kernel 2: gather interleaved bci/wci rows; pad; zero accumulators ------
__global__ __launch_bounds__(256) void scatter(float* __restrict__ ws) {
    int idx = blockIdx.x * blockDim.x + threadIdx.x;
    const float* E_s = ws + WS_ES;
    const float* E_t = ws + WS_ET;
    float4* bci = (float4*)(ws + WS_BCI);
    float4* wci = (float4*)(ws + WS_WCI);
    double* accs = (double*)((char*)ws + WS_ACC_BYTES);

    if (idx < 4 * NSLOT) accs[idx] = 0.0;

    if (idx < NBC) {
        int t = idx >> 2, ii = idx & 3;
        int pi, pj;
        if (t == 0) { pi = 0; pj = 1; }
        else {
            int tt = t - 1;
            pi = 1 + tt / 39;
            int jj = tt % 39;
            pj = (jj < pi) ? jj : jj + 1;
        }
        bci[2*idx]   = *(const float4*)(E_s + (4*pi + ii)*NROW + 4*pj);
        bci[2*idx+1] = *(const float4*)(E_t + (4*pi + ii)*NROW + 4*pj);
    } else if (idx < NBC + NWC) {
        int r = idx - NBC;
        int p = r >> 2;
        wci[2*r]   = *(const float4*)(E_s + r*NROW + 4*p);
        wci[2*r+1] = *(const float4*)(E_t + r*NROW + 4*p);
    } else if (idx < NBC + NWC + NPAD) {
        int p = NBC + (idx - (NBC + NWC));
        float4 pad = make_float4(1e19f, 1e19f, 1e19f, 1e19f);
        bci[2*p] = pad;
        bci[2*p+1] = pad;
    } else if (idx < NBC + NWC + 2*NPAD) {
        int p = NWC + (idx - (NBC + NWC + NPAD));
        float4 pad = make_float4(1e19f, 1e19f, 1e19f, 1e19f);
        wci[2*p] = pad;
        wci[2*p+1] = pad;
    }
}

// --- kernel 3: quad-fused table sweep ----------------------------------------
// Per trip: ONE y-pair load (2 f4) -> 16 evals (4 quad rows x 4 combos), one
// combo accumulator C = (k_ss + k_tt) - (k_st + k_ts). Quad-internal pairs
// live in dedicated tail blocks (no serial lane-0 work in sweeps).
__global__ __launch_bounds__(512, 8) void gk_quad(float* __restrict__ ws) {
    const float4* bci = (const float4*)(ws + WS_BCI);
    const float4* wci = (const float4*)(ws + WS_WCI);
    double* accs = (double*)((char*)ws + WS_ACC_BYTES);

    __shared__ float2 tabs[TAB_N];
    __shared__ float wsum[8][2];

    int tid = threadIdx.x;
    int lane = tid & 63, w = tid >> 6;

    {   // copy PL table global -> LDS (~2.75 float4 per thread)
        const float4* tg = (const float4*)(ws + WS_TAB);
        float4* td = (float4*)tabs;
        for (int k = tid; k < TAB_N / 2; k += 512) td[k] = tg[k];
    }
    __syncthreads();

    auto tab_get = [&](float d) -> float {
        unsigned u = __float_as_uint(d);
        int t = (int)(u >> 16) - TAB_BASE;
        t = min(max(t, 0), TAB_N - 1);
        float2 e = tabs[t];
        return fmaf((float)(u & 0xFFFFu), e.y, e.x);
    };

    float mc = 0.f, md = 0.f;   // combo, st-diag partials

    // combo of one (x-row, y-row) pair given the four float4s
    auto combo = [&](float4 xs_, float4 xt_, float4 ys_, float4 yt_) -> float {
        float d0 = sqd(xs_, ys_), d1 = sqd(xt_, yt_);
        float d2 = sqd(xs_, yt_), d3 = sqd(xt_, ys_);
        return (tab_get(d0) + tab_get(d1)) - (tab_get(d2) + tab_get(d3));
    };

    // quad qa (rows 4qa..4qa+3) vs shared j in [4qa+4, N), phase h of S
    auto quad_sweep = [&](const float4* __restrict__ Yv, int N, int qa,
                          int h, int S) {
        int a = 4 * qa;
        int jbeg = a + 4;
        int T = (N - jbeg + 511) >> 9;
        int trips = (T - h + S - 1) / S;
        if (trips <= 0) return;
        float4 xs0 = Yv[2*a],   xt0 = Yv[2*a+1];
        float4 xs1 = Yv[2*a+2], xt1 = Yv[2*a+3];
        float4 xs2 = Yv[2*a+4], xt2 = Yv[2*a+5];
        float4 xs3 = Yv[2*a+6], xt3 = Yv[2*a+7];
        const float4* Yp = Yv + 2*(jbeg + h*512 + tid);
        int stride = 1024 * S;
        for (int t = 0; t < trips; ++t) {
            float4 ys = Yp[0], yt = Yp[1];
            Yp += stride;
            mc += combo(xs0, xt0, ys, yt) + combo(xs1, xt1, ys, yt)
                + combo(xs2, xt2, ys, yt) + combo(xs3, xt3, ys, yt);
        }
    };

    int b = blockIdx.x;
    int cls;   // 0 = wc (slots 0,1), 1 = bc (slots 2,3)
    if (b < GK_BCS) {                      // bc quad sweep (half phase)
        int pp = b >> 1, h = b & 1;
        cls = 1;
        quad_sweep(bci, NBC, pp,        h, 2);
        quad_sweep(bci, NBC, 1521 - pp, h, 2);
    } else if (b < GK_WCS) {               // wc quad sweep (full)
        int m = b - GK_BCS;
        cls = 0;
        quad_sweep(wci, NWC, m,      0, 1);
        quad_sweep(wci, NWC, 39 - m, 0, 1);
    } else if (b < GK_BD) {                // bc st-diag strip
        cls = 1;
        int i0 = (b - GK_WCS) * 512 + tid;
        if (i0 < NBC) md += tab_get(sqd(bci[2*i0], bci[2*i0+1]));
    } else if (b < GK_WD) {                // wc st-diag strip
        cls = 0;
        if (tid < NWC) md += tab_get(sqd(wci[2*tid], wci[2*tid+1]));
    } else if (b < GK_BI) {                // bc quad-internal pairs
        cls = 1;
        int idx = (b - GK_WD) * 512 + tid;
        if (idx < 1522 * 6) {
            int q = idx / 6, p = idx % 6;
            int ao = (p < 3) ? 0 : ((p < 5) ? 1 : 2);
            int bo = (p < 3) ? (p + 1) : ((p < 5) ? (p - 1) : 3);
            int i = 4*q + ao, j = 4*q + bo;
            mc += combo(bci[2*i], bci[2*i+1], bci[2*j], bci[2*j+1]);
        }
    } else {                               // wc quad-internal pairs
        cls = 0;
        if (tid < 40 * 6) {
            int q = tid / 6, p = tid % 6;
            int ao = (p < 3) ? 0 : ((p < 5) ? 1 : 2);
            int bo = (p < 3) ? (p + 1) : ((p < 5) ? (p - 1) : 3);
            int i = 4*q + ao, j = 4*q + bo;
            mc += combo(wci[2*i], wci[2*i+1], wci[2*j], wci[2*j+1]);
        }
    }

    // wave reduce (f32), cross-wave reduce, 2 atomics per block
    #pragma unroll
    for (int off = 32; off; off >>= 1) {
        mc += __shfl_down(mc, off, 64);
        md += __shfl_down(md, off, 64);
    }
    if (lane == 0) { wsum[w][0] = mc; wsum[w][1] = md; }
    __syncthreads();
    if (tid < 2) {
        double tot = 0.0;
        #pragma unroll
        for (int q = 0; q < 8; ++q) tot += (double)wsum[q][tid];
        if (tot != 0.0)
            atomicAdd(&accs[(cls * 2 + tid) * NSLOT + (b & (NSLOT - 1))], tot);
    }
}

// --- kernel 4: combine into the two output scalars --------------------------
// numerator = 2*combo + 38*N - 2*diag;  out = numerator / N^2
__global__ void finalize(const float* __restrict__ ws, float* __restrict__ out) {
    const double* accs = (const double*)((const char*)ws + WS_ACC_BYTES);
    int lane = threadIdx.x;  // blockDim = 64
    double p[4];
    #pragma unroll
    for (int q = 0; q < 4; ++q) {
        p[q] = accs[q * NSLOT + lane];
        #pragma unroll
        for (int off = 32; off; off >>= 1) p[q] += __shfl_down(p[q], off, 64);
    }
    if (lane == 0) {
        double nw = (double)NWC * (double)NWC;
        double nb = (double)NBC * (double)NBC;
        out[0] = (float)((2.0 * p[0] + 38.0 * NWC - 2.0 * p[1]) / nw);
        out[1] = (float)((2.0 * p[2] + 38.0 * NBC - 2.0 * p[3]) / nb);
    }
}

extern "C" void kernel_launch(void* const* d_in, const int* in_sizes, int n_in,
                              void* d_out, int out_size, void* d_ws, size_t ws_size,
                              hipStream_t stream) {
    const float* src = (const float*)d_in[0];
    const float* tgt = (const float*)d_in[1];
    float* out = (float*)d_out;
    float* ws = (float*)d_ws;

    static const double SIG[19] = {1e-06, 1e-05, 1e-04, 1e-03, 1e-02, 1e-01,
                                   1.0, 5.0, 10.0, 15.0, 20.0, 25.0, 30.0,
                                   35.0, 100.0, 1e3, 1e4, 1e5, 1e6};
    Coef co;
    for (int k = 0; k < 19; ++k)
        co.c[k] = (float)(-1.0 / (2.0 * SIG[k] * 0.6931471805599453));  // -log2e/(2s)

    compute_E_tab<<<211, 256, 0, stream>>>(src, tgt, ws, co);
    scatter<<<29, 256, 0, stream>>>(ws);
    gk_quad<<<GK_GRID, 512, 0, stream>>>(ws);
    finalize<<<1, 64, 0, stream>>>(ws, out);
}